// Round 5
// baseline (173.830 us; speedup 1.0000x reference)
//
#include <hip/hip_runtime.h>
#include <stdint.h>

// Problem constants (fixed by the reference)
#define BB   2
#define SS   2048
#define DD   768
#define HH   12
#define MM   (BB*SS)          // 4096 rows in all GEMMs
#define XSZ  (MM*DD)          // 3,145,728
#define WSZ  (DD*DD)          //   589,824

typedef __bf16 v8bf __attribute__((ext_vector_type(8)));   // 8 bf16 = 4 VGPRs (MFMA A/B frag)
typedef float  v4f  __attribute__((ext_vector_type(4)));   // MFMA C/D frag (16x16)

__device__ inline v4f mfma16(v8bf a, v8bf b, v4f c) {
    return __builtin_amdgcn_mfma_f32_16x16x32_bf16(a, b, c, 0, 0, 0);
}

// float -> bf16 bits, round-to-nearest-even
__device__ inline unsigned short f2bf(float f) {
    union { float f; uint32_t u; } v; v.f = f;
    return (unsigned short)((v.u + 0x7FFFu + ((v.u >> 16) & 1u)) >> 16);
}

// 8 contiguous fp32 -> 8 bf16 packed into 16 bytes (VGPR staging path)
__device__ inline uint4 cvt8(const float* __restrict__ p) {
    uint4 out;
    unsigned short* s = (unsigned short*)&out;
#pragma unroll
    for (int j = 0; j < 8; ++j) s[j] = f2bf(p[j]);
    return out;
}

// Async 16B global->LDS copy (gfx950). LDS dest is wave-uniform base + lane*16B.
__device__ __forceinline__ void gld_lds16(const unsigned short* g, unsigned short* l) {
    __builtin_amdgcn_global_load_lds(
        (const __attribute__((address_space(1))) void*)g,
        (__attribute__((address_space(3))) void*)l, 16, 0, 0);
}

// ---------------------------------------------------------------------------
// R19 (bisect): conversion kernel for the fast path. Flat 1024-elem blocks
// over [Wq|Wk|Wv (3*WSZ) -> Wqb] [X (XSZ) -> Xb]. Region boundary 3*WSZ is
// 1024-aligned (1728 blocks) so the branch is block-uniform. 4800 blocks.
// ---------------------------------------------------------------------------
__global__ __launch_bounds__(256) void cvt_x3(
    const float* __restrict__ Wq, const float* __restrict__ Wk,
    const float* __restrict__ Wv, const float* __restrict__ X,
    unsigned short* __restrict__ Wqb,   // 3*WSZ contiguous (in d_out)
    unsigned short* __restrict__ Xb)    // XSZ (in d_ws)
{
    long i4 = ((long)blockIdx.x * 256 + threadIdx.x) * 4;
    const float* s; unsigned short* d; long off;
    if (i4 < 3L * WSZ) {
        int t = (int)(i4 / WSZ); off = i4 - (long)t * WSZ;
        s = (t == 0) ? Wq : (t == 1) ? Wk : Wv; d = Wqb + (size_t)t * WSZ;
    } else {
        off = i4 - 3L * WSZ; s = X; d = Xb;
    }
    float4 v = *(const float4*)(s + off);
    ushort4 o;
    o.x = f2bf(v.x); o.y = f2bf(v.y); o.z = f2bf(v.z); o.w = f2bf(v.w);
    *(ushort4*)(d + off) = o;
}

// R16-verified converters (fallback path + Wo conversion on both paths).
__global__ __launch_bounds__(256) void cvt_w3(
    const float* __restrict__ Wq, const float* __restrict__ Wk,
    const float* __restrict__ Wv, unsigned short* __restrict__ dst)
{
    long i4 = ((long)blockIdx.x * 256 + threadIdx.x) * 4;
    int t = (int)(i4 / WSZ);
    long off = i4 - (long)t * WSZ;
    const float* s = (t == 0) ? Wq : (t == 1) ? Wk : Wv;
    float4 v = *(const float4*)(s + off);
    ushort4 o;
    o.x = f2bf(v.x); o.y = f2bf(v.y); o.z = f2bf(v.z); o.w = f2bf(v.w);
    *(ushort4*)(dst + (size_t)t * WSZ + off) = o;
}
__global__ __launch_bounds__(256) void cvt_wo(
    const float* __restrict__ Wo, unsigned short* __restrict__ dst)
{
    long i4 = ((long)blockIdx.x * 256 + threadIdx.x) * 4;
    float4 v = *(const float4*)(Wo + i4);
    ushort4 o;
    o.x = f2bf(v.x); o.y = f2bf(v.y); o.z = f2bf(v.z); o.w = f2bf(v.w);
    *(ushort4*)(dst + i4) = o;
}

// ---------------------------------------------------------------------------
// R17/R19: QKV projection, 128x128 tile over the CONCATENATED output (N=2304;
// 768%128==0 so a tile never straddles a weight). 64 MFMA/wave per BK=64 step
// over 32KB staged (4 MFMA/KB, m97-ladder structure). A is bf16 (pre-converted)
// so BOTH operands stage via global_load_lds. All LDS XOR-swizzled
// byte^=((row&7)<<4), source col pre-swizzled (both-sides involution).
// Grid (18,32)=576, XCD-chunked (576%8==0). 4 waves 2x2, wave tile 64x64,
// acc 4x4. Per-element accumulation order unchanged (K ascending).
// Bounds audit (R18): A max elem = 4095*768+760+8 = XSZ exactly; B max elem =
// 767*768+760+8 = WSZ exactly; LDS staging covers bytes [0,16384) exactly;
// epilogue Vo max index = XSZ-1. All in bounds.
// ---------------------------------------------------------------------------
__global__ __launch_bounds__(256) void gemm_qkv128(
    const unsigned short* __restrict__ Xb,
    const unsigned short* __restrict__ Wq,
    const unsigned short* __restrict__ Wk,
    const unsigned short* __restrict__ Wv,
    unsigned short* __restrict__ Qo,
    unsigned short* __restrict__ Ko,
    unsigned short* __restrict__ Vo)
{
    __shared__ __align__(16) unsigned short As[128 * 64];
    __shared__ __align__(16) unsigned short Bs[128 * 64];

    const int flat = (int)(blockIdx.y * gridDim.x + blockIdx.x);   // gx=18
    const int sw   = (flat & 7) * 72 + (flat >> 3);                // XCD-chunked
    const int m0   = (sw / 18) * 128;
    const int ncat = (sw % 18) * 128;
    const int z    = ncat / DD;                 // which weight (block-uniform)
    const int n0   = ncat - z * DD;             // col within weight

    const unsigned short* W = (z == 0) ? Wq : (z == 1) ? Wk : Wv;

    const int tid  = threadIdx.x;
    const int wave = tid >> 6, lane = tid & 63;
    const int quad = lane >> 4, l16 = lane & 15;
    const int waveM = (wave >> 1) * 64, waveN = (wave & 1) * 64;

    // Staging: chunk c (4KB) covers rows c*32 + wave*8 + (lane>>3); LDS linear,
    // source col pre-swizzled by row&7 == lane>>3.
    const int rB  = wave * 8 + (lane >> 3);
    const int cB  = ((lane & 7) ^ (lane >> 3)) * 8;
    const int swz = (l16 & 7) << 4;             // read-side XOR (bytes)

    v4f acc[4][4] = {};

    const unsigned short* a0 = Xb + (size_t)(m0 + rB) * DD + cB;
    const unsigned short* b0 = W  + (size_t)(n0 + rB) * DD + cB;

    for (int kt = 0; kt < DD; kt += 64) {
        __syncthreads();                        // prev-iter frag reads done
#pragma unroll
        for (int c = 0; c < 4; ++c) {
            gld_lds16(a0 + kt + (size_t)(c * 32) * DD, &As[c * 2048 + wave * 512]);
            gld_lds16(b0 + kt + (size_t)(c * 32) * DD, &Bs[c * 2048 + wave * 512]);
        }
        __syncthreads();                        // drain vm: tiles resident

#pragma unroll
        for (int kf = 0; kf < 2; ++kf) {
            v8bf af[4], bfr[4];
#pragma unroll
            for (int i = 0; i < 4; ++i) {
                af[i]  = *(const v8bf*)((const char*)As +
                          (size_t)(waveM + i * 16 + l16) * 128 + ((kf * 64 + quad * 16) ^ swz));
                bfr[i] = *(const v8bf*)((const char*)Bs +
                          (size_t)(waveN + i * 16 + l16) * 128 + ((kf * 64 + quad * 16) ^ swz));
            }
#pragma unroll
            for (int mi = 0; mi < 4; ++mi)
#pragma unroll
                for (int ni = 0; ni < 4; ++ni)
                    acc[mi][ni] = mfma16(af[mi], bfr[ni], acc[mi][ni]);
        }
    }

    // Epilogue: C/D layout col=l16, row=quad*4+r (verified formula).
#pragma unroll
    for (int mi = 0; mi < 4; ++mi)
#pragma unroll
        for (int ni = 0; ni < 4; ++ni)
#pragma unroll
            for (int r = 0; r < 4; ++r) {
                const int row = m0 + waveM + mi * 16 + quad * 4 + r;
                const int col = n0 + waveN + ni * 16 + l16;
                const unsigned short val = f2bf(acc[mi][ni][r]);
                if (z == 0)      Qo[(size_t)row * DD + col] = val;
                else if (z == 1) Ko[(size_t)row * DD + col] = val;
                else {
                    const int b = row >> 11, s = row & 2047;
                    const int h = col >> 6,  dk = col & 63;
                    Vo[(((size_t)(b * HH + h)) * 64 + dk) * SS + s] = val;
                }
            }
}

// ---------------------------------------------------------------------------
// R16-verified fused 64x64 QKV (cvt8 fp32 A path) -- fallback when ws is small.
// ---------------------------------------------------------------------------
__global__ __launch_bounds__(256) void gemm_qkv64(
    const float* __restrict__ X,
    const unsigned short* __restrict__ Wq,
    const unsigned short* __restrict__ Wk,
    const unsigned short* __restrict__ Wv,
    unsigned short* __restrict__ Qo,
    unsigned short* __restrict__ Ko,
    unsigned short* __restrict__ Vo)
{
    __shared__ __align__(16) unsigned short As[64 * 64];
    __shared__ __align__(16) unsigned short Bs[3][64 * 64];

    const int flat = (int)(blockIdx.y * gridDim.x + blockIdx.x);
    const int sw   = (flat & 7) * 96 + (flat >> 3);
    const int m0   = (sw / 12) * 64;
    const int n0   = (sw % 12) * 64;

    const int tid  = threadIdx.x;
    const int wave = tid >> 6, lane = tid & 63;
    const int quad = lane >> 4, l16 = lane & 15;
    const int waveM = (wave >> 1) * 32, waveN = (wave & 1) * 32;

    const int rA  = tid >> 2;
    const int cA  = (tid & 3) * 16;
    const int rxA = (rA & 7) << 4;

    const int rB  = wave * 8 + (lane >> 3);
    const int cB  = ((lane & 7) ^ (lane >> 3)) * 8;
    const int swz = (l16 & 7) << 4;

    v4f acc[3][2][2] = {};

    const float* ap0 = X + (size_t)(m0 + rA) * DD + cA;
    const unsigned short* w0 = Wq + (size_t)(n0 + rB) * DD + cB;
    const unsigned short* w1 = Wk + (size_t)(n0 + rB) * DD + cB;
    const unsigned short* w2 = Wv + (size_t)(n0 + rB) * DD + cB;

    for (int kt = 0; kt < DD; kt += 64) {
        __syncthreads();
        *(uint4*)((char*)As + rA * 128 + ((cA * 2)      ^ rxA)) = cvt8(ap0 + kt);
        *(uint4*)((char*)As + rA * 128 + ((cA * 2 + 16) ^ rxA)) = cvt8(ap0 + kt + 8);
        gld_lds16(w0 + kt,           &Bs[0][wave * 512]);
        gld_lds16(w0 + kt + 32 * DD, &Bs[0][2048 + wave * 512]);
        gld_lds16(w1 + kt,           &Bs[1][wave * 512]);
        gld_lds16(w1 + kt + 32 * DD, &Bs[1][2048 + wave * 512]);
        gld_lds16(w2 + kt,           &Bs[2][wave * 512]);
        gld_lds16(w2 + kt + 32 * DD, &Bs[2][2048 + wave * 512]);
        __syncthreads();

        v8bf af[2][2];
#pragma unroll
        for (int mi = 0; mi < 2; ++mi) {
            const char* arow = (const char*)As + (size_t)(waveM + mi * 16 + l16) * 128;
#pragma unroll
            for (int kf = 0; kf < 2; ++kf)
                af[mi][kf] = *(const v8bf*)(arow + ((kf * 64 + quad * 16) ^ swz));
        }
#pragma unroll
        for (int z = 0; z < 3; ++z) {
            v8bf bfr[2][2];
#pragma unroll
            for (int ni = 0; ni < 2; ++ni) {
                const char* brow = (const char*)&Bs[z][0] + (size_t)(waveN + ni * 16 + l16) * 128;
#pragma unroll
                for (int kf = 0; kf < 2; ++kf)
                    bfr[ni][kf] = *(const v8bf*)(brow + ((kf * 64 + quad * 16) ^ swz));
            }
#pragma unroll
            for (int mi = 0; mi < 2; ++mi)
#pragma unroll
                for (int ni = 0; ni < 2; ++ni) {
                    acc[z][mi][ni] = mfma16(af[mi][0], bfr[ni][0], acc[z][mi][ni]);
                    acc[z][mi][ni] = mfma16(af[mi][1], bfr[ni][1], acc[z][mi][ni]);
                }
        }
    }

#pragma unroll
    for (int mi = 0; mi < 2; ++mi)
#pragma unroll
        for (int ni = 0; ni < 2; ++ni)
#pragma unroll
            for (int r = 0; r < 4; ++r) {
                const int row = m0 + waveM + mi * 16 + quad * 4 + r;
                const int col = n0 + waveN + ni * 16 + l16;
                Qo[(size_t)row * DD + col] = f2bf(acc[0][mi][ni][r]);
                Ko[(size_t)row * DD + col] = f2bf(acc[1][mi][ni][r]);
                const int b = row >> 11, s = row & 2047;
                const int h = col >> 6,  dk = col & 63;
                Vo[(((size_t)(b * HH + h)) * 64 + dk) * SS + s] = f2bf(acc[2][mi][ni][r]);
            }
}

// ---------------------------------------------------------------------------
// R16-verified NT GEMM, 64x64 tile (out-projection). BK=32, 4 waves 2x2, each
// wave 32x32 (acc 2x2). Both operands bf16 via global_load_lds. fp32 epilogue.
// (Reverted to this from R17's gemm_o as part of the bisect.)
// ---------------------------------------------------------------------------
template<int A_ASYNC, int W_ASYNC, int C_F32>
__global__ __launch_bounds__(256) void gemm_64(
    const void* __restrict__ Ain, const void* __restrict__ W0,
    void* __restrict__ C0)
{
    const int K = DD, N = DD;
    const void* W = W0;
    void* C = C0;

    __shared__ __align__(16) unsigned short As[64 * 32];
    __shared__ __align__(16) unsigned short Bs[64 * 32];

    const int tid  = threadIdx.x;
    const int wave = tid >> 6, lane = tid & 63;
    const int quad = lane >> 4, l16 = lane & 15;
    const int waveM = (wave >> 1) * 32, waveN = (wave & 1) * 32;
    const int m0 = blockIdx.y * 64, n0 = blockIdx.x * 64;

    const int rS = (tid >> 2), cS = (tid & 3) * 8;   // e = tid*8 -> row, col in 64x32 tile

    v4f acc[2][2] = {};

    for (int kt = 0; kt < K; kt += 32) {
        __syncthreads();
        if (A_ASYNC)
            gld_lds16((const unsigned short*)Ain + (size_t)(m0 + rS) * K + kt + cS,
                      &As[wave * 512]);
        else
            *(uint4*)(&As[tid * 8]) = cvt8((const float*)Ain + (size_t)(m0 + rS) * K + kt + cS);
        if (W_ASYNC)
            gld_lds16((const unsigned short*)W + (size_t)(n0 + rS) * K + kt + cS,
                      &Bs[wave * 512]);
        else
            *(uint4*)(&Bs[tid * 8]) = cvt8((const float*)W + (size_t)(n0 + rS) * K + kt + cS);
        __syncthreads();   // drains vm + ds for staging

        v8bf af[2], bf[2];
#pragma unroll
        for (int i = 0; i < 2; ++i) {
            af[i] = *(const v8bf*)(&As[(waveM + i * 16 + l16) * 32 + quad * 8]);
            bf[i] = *(const v8bf*)(&Bs[(waveN + i * 16 + l16) * 32 + quad * 8]);
        }
#pragma unroll
        for (int mi = 0; mi < 2; ++mi)
#pragma unroll
            for (int ni = 0; ni < 2; ++ni)
                acc[mi][ni] = mfma16(af[mi], bf[ni], acc[mi][ni]);
    }

    // Epilogue: C/D layout col=l16, row=quad*4+r (verified formula)
#pragma unroll
    for (int mi = 0; mi < 2; ++mi)
#pragma unroll
        for (int ni = 0; ni < 2; ++ni)
#pragma unroll
            for (int r = 0; r < 4; ++r) {
                int row = m0 + waveM + mi * 16 + quad * 4 + r;
                int col = n0 + waveN + ni * 16 + l16;
                if (C_F32) {
                    ((float*)C)[(size_t)row * N + col] = acc[mi][ni][r];
                } else {
                    ((unsigned short*)C)[(size_t)row * N + col] = f2bf(acc[mi][ni][r]);
                }
            }
}

// ---------------------------------------------------------------------------
// R15 attention (verified): LDS-staged, wave-private q-strips, double-buffered
// K/V via global_load_lds with XOR-swizzle (source-preswizzled), one barrier
// per tile, no merge phase. Unchanged.
// ---------------------------------------------------------------------------
__global__ __launch_bounds__(256, 3) void attn_ls(
    const unsigned short* Q,                 // (B,S,D) bf16 (aliases O)
    const unsigned short* __restrict__ Kg,   // (B,S,D) bf16
    const unsigned short* __restrict__ Vt,   // (B,H,64,S) bf16 transposed
    unsigned short* O)                       // (B,S,D) bf16
{
    const int h = blockIdx.x, b = blockIdx.y;
    const int qs = (SS / 64 - 1 - (int)blockIdx.z) * 64;   // LPT: heavy first
    const int tid  = threadIdx.x;
    const int wave = tid >> 6, lane = tid & 63;
    const int quad = lane >> 4, l16 = lane & 15;
    const int qw = qs + wave * 16;           // this wave's private q rows
    const float scale = 0.125f;              // 1/sqrt(64)

    __shared__ __align__(16) unsigned short Ks[2][4096];   // 2 x 64x64 bf16, swizzled
    __shared__ __align__(16) unsigned short Vs[2][4096];   // 2 x 64x64 bf16, swizzled
    __shared__ __align__(16) unsigned short Ps[4][16 * 72];// per-wave P buffer

    // Q frags for this wave's 16 rows (read before any O write: in-place safe)
    v8bf qf0, qf1;
    {
        const unsigned short* qp = &Q[((size_t)(b * SS + qw + l16)) * DD + h * 64];
        qf0 = *(const v8bf*)(qp + quad * 8);
        qf1 = *(const v8bf*)(qp + 32 + quad * 8);
    }

    const int NT = qs / 64 + 1;              // causal k-tiles, SAME for all 4 waves
    const char* kgb = (const char*)&Kg[(size_t)(b * SS) * DD + h * 64];
    const char* vgb = (const char*)&Vt[((size_t)(b * HH + h) * 64) * SS];

    const int rA = wave * 8 + (lane >> 3);               // rows rA and rA+32
    const int oA = ((lane & 7) * 16) ^ ((rA & 7) << 4);  // swizzled in-row byte
    const int swz = (l16 & 7) << 4;                      // read-side XOR

    v4f oacc[4] = {};
    float l_run[4] = {0.f, 0.f, 0.f, 0.f};
    unsigned short* pw = &Ps[wave][0];

    // Prologue: stage tile 0 into buffer 0
    gld_lds16((const unsigned short*)(kgb + (size_t)rA        * (DD * 2) + oA), &Ks[0][wave * 512]);
    gld_lds16((const unsigned short*)(kgb + (size_t)(rA + 32) * (DD * 2) + oA), &Ks[0][2048 + wave * 512]);
    gld_lds16((const unsigned short*)(vgb + (size_t)rA        * (SS * 2) + oA), &Vs[0][wave * 512]);
    gld_lds16((const unsigned short*)(vgb + (size_t)(rA + 32) * (SS * 2) + oA), &Vs[0][2048 + wave * 512]);
    __syncthreads();   // drains vmcnt: tile 0 resident

    for (int kt = 0; kt < NT; ++kt) {
        const int cur = kt & 1;
        const int kb  = kt * 64;

        // Async-stage NEXT tile into the other buffer
        if (kt + 1 < NT) {
            const size_t kb2 = (size_t)(kb + 64);
            gld_lds16((const unsigned short*)(kgb + (kb2 + rA)      * (DD * 2) + oA), &Ks[cur ^ 1][wave * 512]);
            gld_lds16((const unsigned short*)(kgb + (kb2 + rA + 32) * (DD * 2) + oA), &Ks[cur ^ 1][2048 + wave * 512]);
            gld_lds16((const unsigned short*)(vgb + (size_t)rA        * (SS * 2) + kb2 * 2 + oA), &Vs[cur ^ 1][wave * 512]);
            gld_lds16((const unsigned short*)(vgb + (size_t)(rA + 32) * (SS * 2) + kb2 * 2 + oA), &Vs[cur ^ 1][2048 + wave * 512]);
        }

        const char* ksb = (const char*)&Ks[cur][0];
        const char* vsb = (const char*)&Vs[cur][0];

        // K frags from swizzled LDS: row = nk*16+l16, cols half*32 + quad*8..
        v8bf kf0[4], kf1[4];
#pragma unroll
        for (int nk = 0; nk < 4; ++nk) {
            const char* krow = ksb + (size_t)(nk * 16 + l16) * 128;
            kf0[nk] = *(const v8bf*)(krow + ((quad * 16) ^ swz));
            kf1[nk] = *(const v8bf*)(krow + ((64 + quad * 16) ^ swz));
        }

        // S = Q K^T (16 q-rows x 64 keys), f32 accumulate
        v4f sacc[4] = {};
#pragma unroll
        for (int nk = 0; nk < 4; ++nk) {
            sacc[nk] = mfma16(qf0, kf0[nk], sacc[nk]);
            sacc[nk] = mfma16(qf1, kf1[nk], sacc[nk]);
        }

        // fixed-base softmax: p = exp(s/8); mask only on the diagonal tile
        const bool diag = (kt == NT - 1);
        float pv[4][4];
#pragma unroll
        for (int nk = 0; nk < 4; ++nk)
#pragma unroll
            for (int r = 0; r < 4; ++r) {
                float p = __expf(sacc[nk][r] * scale);
                if (diag) {
                    int key  = kb + nk * 16 + l16;
                    int qrow = qw + quad * 4 + r;
                    if (key > qrow) p = 0.0f;
                }
                pv[nk][r] = p;
                l_run[r] += p;
            }

        // V frags (issued before the P round-trip so latency overlaps it)
        v8bf vf[2][4];
#pragma unroll
        for (int kc = 0; kc < 2; ++kc)
#pragma unroll
            for (int dt = 0; dt < 4; ++dt) {
                const char* vr = vsb + (size_t)(dt * 16 + l16) * 128;
                vf[kc][dt] = *(const v8bf*)(vr + ((kc * 64 + quad * 16) ^ swz));
            }

        // P: C-layout -> per-wave LDS (stride 72) -> A-layout frags
#pragma unroll
        for (int nk = 0; nk < 4; ++nk)
#pragma unroll
            for (int r = 0; r < 4; ++r)
                pw[(quad * 4 + r) * 72 + nk * 16 + l16] = f2bf(pv[nk][r]);
        __asm__ volatile("" ::: "memory");

        v8bf pa0 = *(const v8bf*)(&pw[l16 * 72 + quad * 8]);
        v8bf pa1 = *(const v8bf*)(&pw[l16 * 72 + 32 + quad * 8]);
#pragma unroll
        for (int dt = 0; dt < 4; ++dt) oacc[dt] = mfma16(pa0, vf[0][dt], oacc[dt]);
#pragma unroll
        for (int dt = 0; dt < 4; ++dt) oacc[dt] = mfma16(pa1, vf[1][dt], oacc[dt]);

        // One barrier per tile: reads of buf[cur] done + buf[cur^1] resident.
        __syncthreads();
    }

    // Row-sum reduce across the 16 l16-lanes of each quad
    for (int off = 1; off < 16; off <<= 1)
#pragma unroll
        for (int r = 0; r < 4; ++r)
            l_run[r] += __shfl_xor(l_run[r], off, 64);

    float inv[4];
#pragma unroll
    for (int r = 0; r < 4; ++r) inv[r] = 1.0f / l_run[r];

    // Direct per-wave store: lane holds O[qw+quad*4+r][dt*16+l16] (C layout).
    unsigned short* ob = &O[((size_t)(b * SS + qw + quad * 4)) * DD + h * 64 + l16];
#pragma unroll
    for (int r = 0; r < 4; ++r)
#pragma unroll
        for (int dt = 0; dt < 4; ++dt)
            ob[(size_t)r * DD + dt * 16] = f2bf(oacc[dt][r] * inv[r]);
}

// ---------------------------------------------------------------------------
extern "C" void kernel_launch(void* const* d_in, const int* in_sizes, int n_in,
                              void* d_out, int out_size, void* d_ws, size_t ws_size,
                              hipStream_t stream)
{
    const float* X  = (const float*)d_in[0];
    const float* Wq = (const float*)d_in[1];
    const float* Wk = (const float*)d_in[2];
    const float* Wv = (const float*)d_in[3];
    const float* Wo = (const float*)d_in[4];
    float* Out = (float*)d_out;

    // d_ws layout (fast path, needs 3*XSZ u16 = 18.9MB; guard at 25.2MB):
    //   [0,XSZ)      Qb   (Q bf16, later attn output in-place)
    //   [XSZ,2XSZ)   Kb   (K bf16; reused for bf16 Wo after attn)
    //   [2XSZ,3XSZ)  Xb   (X bf16, dead after gemm_qkv128)
    // d_out (2*XSZ u16): [0,XSZ) = V^T bf16 (dead before gemm_64 writes);
    //   [XSZ,+3WSZ) = bf16 Wq,Wk,Wv (dead after the QKV GEMM).
    unsigned short* Qb  = (unsigned short*)d_ws;
    unsigned short* Kb  = Qb + XSZ;
    unsigned short* Xb  = Kb + XSZ;
    unsigned short* Vtb = (unsigned short*)d_out;
    unsigned short* Wqb = Vtb + XSZ;
    unsigned short* Wkb = Wqb + WSZ;
    unsigned short* Wvb = Wkb + WSZ;

    dim3 blk(256);
    dim3 g2(HH, BB, SS / 64);                       // attention grid
    dim3 g3(DD / 64, MM / 64);                      // out-projection grid

    if (ws_size >= (size_t)8 * XSZ) {               // fast path (25.2 MB guard)
        cvt_x3<<<4800, blk, 0, stream>>>(Wq, Wk, Wv, X, Wqb, Xb);

        dim3 g1(2304 / 128, MM / 128);              // 576 blocks: 128x128 QKV
        gemm_qkv128<<<g1, blk, 0, stream>>>(Xb, Wqb, Wkb, Wvb, Qb, Kb, Vtb);

        attn_ls<<<g2, blk, 0, stream>>>(Qb, Kb, Vtb, Qb);

        cvt_wo<<<576, blk, 0, stream>>>(Wo, Kb);    // Kb dead after attn

        gemm_64<1, 1, 1><<<g3, blk, 0, stream>>>(Qb, Kb, Out);
    } else {                                        // R16-verified fallback
        cvt_w3<<<1728, blk, 0, stream>>>(Wq, Wk, Wv, Wqb);

        dim3 g1(DD / 64, MM / 64);
        gemm_qkv64<<<g1, blk, 0, stream>>>(X, Wqb, Wkb, Wvb, Qb, Kb, Vtb);

        attn_ls<<<g2, blk, 0, stream>>>(Qb, Kb, Vtb, Qb);

        cvt_wo<<<576, blk, 0, stream>>>(Wo, Kb);

        gemm_64<1, 1, 1><<<g3, blk, 0, stream>>>(Qb, Kb, Out);
    }
}

// Round 6
// 168.446 us; speedup vs baseline: 1.0320x; 1.0320x over previous
//
#include <hip/hip_runtime.h>
#include <stdint.h>

// Problem constants (fixed by the reference)
#define BB   2
#define SS   2048
#define DD   768
#define HH   12
#define MM   (BB*SS)          // 4096 rows in all GEMMs
#define XSZ  (MM*DD)          // 3,145,728
#define WSZ  (DD*DD)          //   589,824

typedef __bf16 v8bf __attribute__((ext_vector_type(8)));   // 8 bf16 = 4 VGPRs (MFMA A/B frag)
typedef float  v4f  __attribute__((ext_vector_type(4)));   // MFMA C/D frag (16x16)

__device__ inline v4f mfma16(v8bf a, v8bf b, v4f c) {
    return __builtin_amdgcn_mfma_f32_16x16x32_bf16(a, b, c, 0, 0, 0);
}

// float -> bf16 bits, round-to-nearest-even
__device__ inline unsigned short f2bf(float f) {
    union { float f; uint32_t u; } v; v.f = f;
    return (unsigned short)((v.u + 0x7FFFu + ((v.u >> 16) & 1u)) >> 16);
}

// 8 contiguous fp32 -> 8 bf16 packed into 16 bytes (VGPR staging path)
__device__ inline uint4 cvt8(const float* __restrict__ p) {
    uint4 out;
    unsigned short* s = (unsigned short*)&out;
#pragma unroll
    for (int j = 0; j < 8; ++j) s[j] = f2bf(p[j]);
    return out;
}

// Async 16B global->LDS copy (gfx950). LDS dest is wave-uniform base + lane*16B.
__device__ __forceinline__ void gld_lds16(const unsigned short* g, unsigned short* l) {
    __builtin_amdgcn_global_load_lds(
        (const __attribute__((address_space(1))) void*)g,
        (__attribute__((address_space(3))) void*)l, 16, 0, 0);
}

// ---------------------------------------------------------------------------
// R19-verified: conversion kernel for the fast path. Flat 1024-elem blocks
// over [Wq|Wk|Wv (3*WSZ) -> Wqb] [X (XSZ) -> Xb]. Region boundary 3*WSZ is
// 1024-aligned (1728 blocks) so the branch is block-uniform. 4800 blocks.
// ---------------------------------------------------------------------------
__global__ __launch_bounds__(256) void cvt_x3(
    const float* __restrict__ Wq, const float* __restrict__ Wk,
    const float* __restrict__ Wv, const float* __restrict__ X,
    unsigned short* __restrict__ Wqb,   // 3*WSZ contiguous (in d_out)
    unsigned short* __restrict__ Xb)    // XSZ (in d_ws)
{
    long i4 = ((long)blockIdx.x * 256 + threadIdx.x) * 4;
    const float* s; unsigned short* d; long off;
    if (i4 < 3L * WSZ) {
        int t = (int)(i4 / WSZ); off = i4 - (long)t * WSZ;
        s = (t == 0) ? Wq : (t == 1) ? Wk : Wv; d = Wqb + (size_t)t * WSZ;
    } else {
        off = i4 - 3L * WSZ; s = X; d = Xb;
    }
    float4 v = *(const float4*)(s + off);
    ushort4 o;
    o.x = f2bf(v.x); o.y = f2bf(v.y); o.z = f2bf(v.z); o.w = f2bf(v.w);
    *(ushort4*)(d + off) = o;
}

// R16-verified converters (fallback path + Wo conversion on both paths).
__global__ __launch_bounds__(256) void cvt_w3(
    const float* __restrict__ Wq, const float* __restrict__ Wk,
    const float* __restrict__ Wv, unsigned short* __restrict__ dst)
{
    long i4 = ((long)blockIdx.x * 256 + threadIdx.x) * 4;
    int t = (int)(i4 / WSZ);
    long off = i4 - (long)t * WSZ;
    const float* s = (t == 0) ? Wq : (t == 1) ? Wk : Wv;
    float4 v = *(const float4*)(s + off);
    ushort4 o;
    o.x = f2bf(v.x); o.y = f2bf(v.y); o.z = f2bf(v.z); o.w = f2bf(v.w);
    *(ushort4*)(dst + (size_t)t * WSZ + off) = o;
}
__global__ __launch_bounds__(256) void cvt_wo(
    const float* __restrict__ Wo, unsigned short* __restrict__ dst)
{
    long i4 = ((long)blockIdx.x * 256 + threadIdx.x) * 4;
    float4 v = *(const float4*)(Wo + i4);
    ushort4 o;
    o.x = f2bf(v.x); o.y = f2bf(v.y); o.z = f2bf(v.z); o.w = f2bf(v.w);
    *(ushort4*)(dst + i4) = o;
}

// ---------------------------------------------------------------------------
// R20: QKV projection, 128x128 tile, now DOUBLE-BUFFERED (T3 2-phase).
// Why: R19 counters for the single-buffered version (46.5us, MfmaUtil 11%,
// VALUBusy 11%, occupancy 9.6%, FETCH ~compulsory, conflicts 0) showed a
// latency-bound loop: at 2.25 blocks/CU the per-K-step vmcnt(0) drain
// (~500-900cy) serializes with nothing to fill it. Fix: stage K-tile t+1
// BEFORE computing tile t; the staged loads get the whole compute phase
// (32 MFMA/wave + 16 ds_read_b128) to land; one __syncthreads per K-step
// both drains them and protects buf[cur] for overwrite. LDS 64KB -> hard
// 2 blocks/CU (trade judged favorable because baseline overlap is broken).
// Tile over CONCATENATED output (N=2304, 768%128==0 -> no weight straddle).
// All LDS XOR-swizzled byte^=((row&7)<<4), source col pre-swizzled
// (both-sides involution, verified). Grid (18,32)=576, XCD-chunked.
// Per-element accumulation order unchanged (K ascending).
// ---------------------------------------------------------------------------
__global__ __launch_bounds__(256) void gemm_qkv128(
    const unsigned short* __restrict__ Xb,
    const unsigned short* __restrict__ Wq,
    const unsigned short* __restrict__ Wk,
    const unsigned short* __restrict__ Wv,
    unsigned short* __restrict__ Qo,
    unsigned short* __restrict__ Ko,
    unsigned short* __restrict__ Vo)
{
    __shared__ __align__(16) unsigned short As[2][128 * 64];
    __shared__ __align__(16) unsigned short Bs[2][128 * 64];

    const int flat = (int)(blockIdx.y * gridDim.x + blockIdx.x);   // gx=18
    const int sw   = (flat & 7) * 72 + (flat >> 3);                // XCD-chunked
    const int m0   = (sw / 18) * 128;
    const int ncat = (sw % 18) * 128;
    const int z    = ncat / DD;                 // which weight (block-uniform)
    const int n0   = ncat - z * DD;             // col within weight

    const unsigned short* W = (z == 0) ? Wq : (z == 1) ? Wk : Wv;

    const int tid  = threadIdx.x;
    const int wave = tid >> 6, lane = tid & 63;
    const int quad = lane >> 4, l16 = lane & 15;
    const int waveM = (wave >> 1) * 64, waveN = (wave & 1) * 64;

    // Staging: chunk c (4KB) covers rows c*32 + wave*8 + (lane>>3); LDS linear,
    // source col pre-swizzled by row&7 == lane>>3.
    const int rB  = wave * 8 + (lane >> 3);
    const int cB  = ((lane & 7) ^ (lane >> 3)) * 8;
    const int swz = (l16 & 7) << 4;             // read-side XOR (bytes)

    v4f acc[4][4] = {};

    const unsigned short* a0 = Xb + (size_t)(m0 + rB) * DD + cB;
    const unsigned short* b0 = W  + (size_t)(n0 + rB) * DD + cB;

    // Prologue: stage K-tile 0 into buffer 0
#pragma unroll
    for (int c = 0; c < 4; ++c) {
        gld_lds16(a0 + (size_t)(c * 32) * DD, &As[0][c * 2048 + wave * 512]);
        gld_lds16(b0 + (size_t)(c * 32) * DD, &Bs[0][c * 2048 + wave * 512]);
    }
    __syncthreads();                            // tile 0 resident

    int cur = 0;
    for (int kt = 0; kt < DD; kt += 64) {
        if (kt + 64 < DD) {                     // issue NEXT tile first (async)
#pragma unroll
            for (int c = 0; c < 4; ++c) {
                gld_lds16(a0 + kt + 64 + (size_t)(c * 32) * DD,
                          &As[cur ^ 1][c * 2048 + wave * 512]);
                gld_lds16(b0 + kt + 64 + (size_t)(c * 32) * DD,
                          &Bs[cur ^ 1][c * 2048 + wave * 512]);
            }
        }
#pragma unroll
        for (int kf = 0; kf < 2; ++kf) {
            v8bf af[4], bfr[4];
#pragma unroll
            for (int i = 0; i < 4; ++i) {
                af[i]  = *(const v8bf*)((const char*)&As[cur][0] +
                          (size_t)(waveM + i * 16 + l16) * 128 + ((kf * 64 + quad * 16) ^ swz));
                bfr[i] = *(const v8bf*)((const char*)&Bs[cur][0] +
                          (size_t)(waveN + i * 16 + l16) * 128 + ((kf * 64 + quad * 16) ^ swz));
            }
#pragma unroll
            for (int mi = 0; mi < 4; ++mi)
#pragma unroll
                for (int ni = 0; ni < 4; ++ni)
                    acc[mi][ni] = mfma16(af[mi], bfr[ni], acc[mi][ni]);
        }
        __syncthreads();   // reads of buf[cur] done + buf[cur^1] resident
        cur ^= 1;
    }

    // Epilogue: C/D layout col=l16, row=quad*4+r (verified formula).
#pragma unroll
    for (int mi = 0; mi < 4; ++mi)
#pragma unroll
        for (int ni = 0; ni < 4; ++ni)
#pragma unroll
            for (int r = 0; r < 4; ++r) {
                const int row = m0 + waveM + mi * 16 + quad * 4 + r;
                const int col = n0 + waveN + ni * 16 + l16;
                const unsigned short val = f2bf(acc[mi][ni][r]);
                if (z == 0)      Qo[(size_t)row * DD + col] = val;
                else if (z == 1) Ko[(size_t)row * DD + col] = val;
                else {
                    const int b = row >> 11, s = row & 2047;
                    const int h = col >> 6,  dk = col & 63;
                    Vo[(((size_t)(b * HH + h)) * 64 + dk) * SS + s] = val;
                }
            }
}

// ---------------------------------------------------------------------------
// R16-verified fused 64x64 QKV (cvt8 fp32 A path) -- fallback when ws is small.
// ---------------------------------------------------------------------------
__global__ __launch_bounds__(256) void gemm_qkv64(
    const float* __restrict__ X,
    const unsigned short* __restrict__ Wq,
    const unsigned short* __restrict__ Wk,
    const unsigned short* __restrict__ Wv,
    unsigned short* __restrict__ Qo,
    unsigned short* __restrict__ Ko,
    unsigned short* __restrict__ Vo)
{
    __shared__ __align__(16) unsigned short As[64 * 64];
    __shared__ __align__(16) unsigned short Bs[3][64 * 64];

    const int flat = (int)(blockIdx.y * gridDim.x + blockIdx.x);
    const int sw   = (flat & 7) * 96 + (flat >> 3);
    const int m0   = (sw / 12) * 64;
    const int n0   = (sw % 12) * 64;

    const int tid  = threadIdx.x;
    const int wave = tid >> 6, lane = tid & 63;
    const int quad = lane >> 4, l16 = lane & 15;
    const int waveM = (wave >> 1) * 32, waveN = (wave & 1) * 32;

    const int rA  = tid >> 2;
    const int cA  = (tid & 3) * 16;
    const int rxA = (rA & 7) << 4;

    const int rB  = wave * 8 + (lane >> 3);
    const int cB  = ((lane & 7) ^ (lane >> 3)) * 8;
    const int swz = (l16 & 7) << 4;

    v4f acc[3][2][2] = {};

    const float* ap0 = X + (size_t)(m0 + rA) * DD + cA;
    const unsigned short* w0 = Wq + (size_t)(n0 + rB) * DD + cB;
    const unsigned short* w1 = Wk + (size_t)(n0 + rB) * DD + cB;
    const unsigned short* w2 = Wv + (size_t)(n0 + rB) * DD + cB;

    for (int kt = 0; kt < DD; kt += 64) {
        __syncthreads();
        *(uint4*)((char*)As + rA * 128 + ((cA * 2)      ^ rxA)) = cvt8(ap0 + kt);
        *(uint4*)((char*)As + rA * 128 + ((cA * 2 + 16) ^ rxA)) = cvt8(ap0 + kt + 8);
        gld_lds16(w0 + kt,           &Bs[0][wave * 512]);
        gld_lds16(w0 + kt + 32 * DD, &Bs[0][2048 + wave * 512]);
        gld_lds16(w1 + kt,           &Bs[1][wave * 512]);
        gld_lds16(w1 + kt + 32 * DD, &Bs[1][2048 + wave * 512]);
        gld_lds16(w2 + kt,           &Bs[2][wave * 512]);
        gld_lds16(w2 + kt + 32 * DD, &Bs[2][2048 + wave * 512]);
        __syncthreads();

        v8bf af[2][2];
#pragma unroll
        for (int mi = 0; mi < 2; ++mi) {
            const char* arow = (const char*)As + (size_t)(waveM + mi * 16 + l16) * 128;
#pragma unroll
            for (int kf = 0; kf < 2; ++kf)
                af[mi][kf] = *(const v8bf*)(arow + ((kf * 64 + quad * 16) ^ swz));
        }
#pragma unroll
        for (int z = 0; z < 3; ++z) {
            v8bf bfr[2][2];
#pragma unroll
            for (int ni = 0; ni < 2; ++ni) {
                const char* brow = (const char*)&Bs[z][0] + (size_t)(waveN + ni * 16 + l16) * 128;
#pragma unroll
                for (int kf = 0; kf < 2; ++kf)
                    bfr[ni][kf] = *(const v8bf*)(brow + ((kf * 64 + quad * 16) ^ swz));
            }
#pragma unroll
            for (int mi = 0; mi < 2; ++mi)
#pragma unroll
                for (int ni = 0; ni < 2; ++ni) {
                    acc[z][mi][ni] = mfma16(af[mi][0], bfr[ni][0], acc[z][mi][ni]);
                    acc[z][mi][ni] = mfma16(af[mi][1], bfr[ni][1], acc[z][mi][ni]);
                }
        }
    }

#pragma unroll
    for (int mi = 0; mi < 2; ++mi)
#pragma unroll
        for (int ni = 0; ni < 2; ++ni)
#pragma unroll
            for (int r = 0; r < 4; ++r) {
                const int row = m0 + waveM + mi * 16 + quad * 4 + r;
                const int col = n0 + waveN + ni * 16 + l16;
                Qo[(size_t)row * DD + col] = f2bf(acc[0][mi][ni][r]);
                Ko[(size_t)row * DD + col] = f2bf(acc[1][mi][ni][r]);
                const int b = row >> 11, s = row & 2047;
                const int h = col >> 6,  dk = col & 63;
                Vo[(((size_t)(b * HH + h)) * 64 + dk) * SS + s] = f2bf(acc[2][mi][ni][r]);
            }
}

// ---------------------------------------------------------------------------
// R20 out-projection: 64x64, BK=64, BOTH operands via global_load_lds
// (source pre-swizzled), double-buffered LDS, T3 2-phase (stage kt+1 before
// computing kt, one __syncthreads per K-step). Same structure as gemm_qkv128's
// loop. Grid (12,64)=768 = 3/CU, XCD-chunked. LDS 32KB.
// ---------------------------------------------------------------------------
__global__ __launch_bounds__(256) void gemm_o(
    const unsigned short* __restrict__ A,
    const unsigned short* __restrict__ W,
    float* __restrict__ C)
{
    __shared__ __align__(16) unsigned short As[2][64 * 64];
    __shared__ __align__(16) unsigned short Bs[2][64 * 64];

    const int flat = (int)(blockIdx.y * gridDim.x + blockIdx.x);  // gx=12
    const int sw   = (flat & 7) * 96 + (flat >> 3);
    const int m0   = (sw / 12) * 64;
    const int n0   = (sw % 12) * 64;

    const int tid  = threadIdx.x;
    const int wave = tid >> 6, lane = tid & 63;
    const int quad = lane >> 4, l16 = lane & 15;
    const int waveM = (wave >> 1) * 32, waveN = (wave & 1) * 32;

    const int rB  = wave * 8 + (lane >> 3);
    const int cB  = ((lane & 7) ^ (lane >> 3)) * 8;
    const int swz = (l16 & 7) << 4;

    const unsigned short* a0 = A + (size_t)(m0 + rB) * DD + cB;
    const unsigned short* b0 = W + (size_t)(n0 + rB) * DD + cB;

    v4f acc[2][2] = {};

    // Prologue: stage tile 0 into buffer 0
    gld_lds16(a0,           &As[0][wave * 512]);
    gld_lds16(a0 + 32 * DD, &As[0][2048 + wave * 512]);
    gld_lds16(b0,           &Bs[0][wave * 512]);
    gld_lds16(b0 + 32 * DD, &Bs[0][2048 + wave * 512]);
    __syncthreads();

    int cur = 0;
    for (int kt = 0; kt < DD; kt += 64) {
        if (kt + 64 < DD) {                     // stage NEXT tile (async)
            gld_lds16(a0 + kt + 64,           &As[cur ^ 1][wave * 512]);
            gld_lds16(a0 + kt + 64 + 32 * DD, &As[cur ^ 1][2048 + wave * 512]);
            gld_lds16(b0 + kt + 64,           &Bs[cur ^ 1][wave * 512]);
            gld_lds16(b0 + kt + 64 + 32 * DD, &Bs[cur ^ 1][2048 + wave * 512]);
        }
#pragma unroll
        for (int kf = 0; kf < 2; ++kf) {
            v8bf af[2], bfr[2];
#pragma unroll
            for (int i = 0; i < 2; ++i) {
                af[i]  = *(const v8bf*)((const char*)&As[cur][0] +
                          (size_t)(waveM + i * 16 + l16) * 128 + ((kf * 64 + quad * 16) ^ swz));
                bfr[i] = *(const v8bf*)((const char*)&Bs[cur][0] +
                          (size_t)(waveN + i * 16 + l16) * 128 + ((kf * 64 + quad * 16) ^ swz));
            }
#pragma unroll
            for (int mi = 0; mi < 2; ++mi)
#pragma unroll
                for (int ni = 0; ni < 2; ++ni)
                    acc[mi][ni] = mfma16(af[mi], bfr[ni], acc[mi][ni]);
        }
        __syncthreads();   // frag reads of buf[cur] done + buf[cur^1] resident
        cur ^= 1;
    }

#pragma unroll
    for (int mi = 0; mi < 2; ++mi)
#pragma unroll
        for (int ni = 0; ni < 2; ++ni)
#pragma unroll
            for (int r = 0; r < 4; ++r) {
                const int row = m0 + waveM + mi * 16 + quad * 4 + r;
                const int col = n0 + waveN + ni * 16 + l16;
                C[(size_t)row * DD + col] = acc[mi][ni][r];
            }
}

// ---------------------------------------------------------------------------
// R15 attention (verified): LDS-staged, wave-private q-strips, double-buffered
// K/V via global_load_lds with XOR-swizzle (source-preswizzled), one barrier
// per tile, no merge phase. Unchanged.
// ---------------------------------------------------------------------------
__global__ __launch_bounds__(256, 3) void attn_ls(
    const unsigned short* Q,                 // (B,S,D) bf16 (aliases O)
    const unsigned short* __restrict__ Kg,   // (B,S,D) bf16
    const unsigned short* __restrict__ Vt,   // (B,H,64,S) bf16 transposed
    unsigned short* O)                       // (B,S,D) bf16
{
    const int h = blockIdx.x, b = blockIdx.y;
    const int qs = (SS / 64 - 1 - (int)blockIdx.z) * 64;   // LPT: heavy first
    const int tid  = threadIdx.x;
    const int wave = tid >> 6, lane = tid & 63;
    const int quad = lane >> 4, l16 = lane & 15;
    const int qw = qs + wave * 16;           // this wave's private q rows
    const float scale = 0.125f;              // 1/sqrt(64)

    __shared__ __align__(16) unsigned short Ks[2][4096];   // 2 x 64x64 bf16, swizzled
    __shared__ __align__(16) unsigned short Vs[2][4096];   // 2 x 64x64 bf16, swizzled
    __shared__ __align__(16) unsigned short Ps[4][16 * 72];// per-wave P buffer

    // Q frags for this wave's 16 rows (read before any O write: in-place safe)
    v8bf qf0, qf1;
    {
        const unsigned short* qp = &Q[((size_t)(b * SS + qw + l16)) * DD + h * 64];
        qf0 = *(const v8bf*)(qp + quad * 8);
        qf1 = *(const v8bf*)(qp + 32 + quad * 8);
    }

    const int NT = qs / 64 + 1;              // causal k-tiles, SAME for all 4 waves
    const char* kgb = (const char*)&Kg[(size_t)(b * SS) * DD + h * 64];
    const char* vgb = (const char*)&Vt[((size_t)(b * HH + h) * 64) * SS];

    const int rA = wave * 8 + (lane >> 3);               // rows rA and rA+32
    const int oA = ((lane & 7) * 16) ^ ((rA & 7) << 4);  // swizzled in-row byte
    const int swz = (l16 & 7) << 4;                      // read-side XOR

    v4f oacc[4] = {};
    float l_run[4] = {0.f, 0.f, 0.f, 0.f};
    unsigned short* pw = &Ps[wave][0];

    // Prologue: stage tile 0 into buffer 0
    gld_lds16((const unsigned short*)(kgb + (size_t)rA        * (DD * 2) + oA), &Ks[0][wave * 512]);
    gld_lds16((const unsigned short*)(kgb + (size_t)(rA + 32) * (DD * 2) + oA), &Ks[0][2048 + wave * 512]);
    gld_lds16((const unsigned short*)(vgb + (size_t)rA        * (SS * 2) + oA), &Vs[0][wave * 512]);
    gld_lds16((const unsigned short*)(vgb + (size_t)(rA + 32) * (SS * 2) + oA), &Vs[0][2048 + wave * 512]);
    __syncthreads();   // drains vmcnt: tile 0 resident

    for (int kt = 0; kt < NT; ++kt) {
        const int cur = kt & 1;
        const int kb  = kt * 64;

        // Async-stage NEXT tile into the other buffer
        if (kt + 1 < NT) {
            const size_t kb2 = (size_t)(kb + 64);
            gld_lds16((const unsigned short*)(kgb + (kb2 + rA)      * (DD * 2) + oA), &Ks[cur ^ 1][wave * 512]);
            gld_lds16((const unsigned short*)(kgb + (kb2 + rA + 32) * (DD * 2) + oA), &Ks[cur ^ 1][2048 + wave * 512]);
            gld_lds16((const unsigned short*)(vgb + (size_t)rA        * (SS * 2) + kb2 * 2 + oA), &Vs[cur ^ 1][wave * 512]);
            gld_lds16((const unsigned short*)(vgb + (size_t)(rA + 32) * (SS * 2) + kb2 * 2 + oA), &Vs[cur ^ 1][2048 + wave * 512]);
        }

        const char* ksb = (const char*)&Ks[cur][0];
        const char* vsb = (const char*)&Vs[cur][0];

        // K frags from swizzled LDS: row = nk*16+l16, cols half*32 + quad*8..
        v8bf kf0[4], kf1[4];
#pragma unroll
        for (int nk = 0; nk < 4; ++nk) {
            const char* krow = ksb + (size_t)(nk * 16 + l16) * 128;
            kf0[nk] = *(const v8bf*)(krow + ((quad * 16) ^ swz));
            kf1[nk] = *(const v8bf*)(krow + ((64 + quad * 16) ^ swz));
        }

        // S = Q K^T (16 q-rows x 64 keys), f32 accumulate
        v4f sacc[4] = {};
#pragma unroll
        for (int nk = 0; nk < 4; ++nk) {
            sacc[nk] = mfma16(qf0, kf0[nk], sacc[nk]);
            sacc[nk] = mfma16(qf1, kf1[nk], sacc[nk]);
        }

        // fixed-base softmax: p = exp(s/8); mask only on the diagonal tile
        const bool diag = (kt == NT - 1);
        float pv[4][4];
#pragma unroll
        for (int nk = 0; nk < 4; ++nk)
#pragma unroll
            for (int r = 0; r < 4; ++r) {
                float p = __expf(sacc[nk][r] * scale);
                if (diag) {
                    int key  = kb + nk * 16 + l16;
                    int qrow = qw + quad * 4 + r;
                    if (key > qrow) p = 0.0f;
                }
                pv[nk][r] = p;
                l_run[r] += p;
            }

        // V frags (issued before the P round-trip so latency overlaps it)
        v8bf vf[2][4];
#pragma unroll
        for (int kc = 0; kc < 2; ++kc)
#pragma unroll
            for (int dt = 0; dt < 4; ++dt) {
                const char* vr = vsb + (size_t)(dt * 16 + l16) * 128;
                vf[kc][dt] = *(const v8bf*)(vr + ((kc * 64 + quad * 16) ^ swz));
            }

        // P: C-layout -> per-wave LDS (stride 72) -> A-layout frags
#pragma unroll
        for (int nk = 0; nk < 4; ++nk)
#pragma unroll
            for (int r = 0; r < 4; ++r)
                pw[(quad * 4 + r) * 72 + nk * 16 + l16] = f2bf(pv[nk][r]);
        __asm__ volatile("" ::: "memory");

        v8bf pa0 = *(const v8bf*)(&pw[l16 * 72 + quad * 8]);
        v8bf pa1 = *(const v8bf*)(&pw[l16 * 72 + 32 + quad * 8]);
#pragma unroll
        for (int dt = 0; dt < 4; ++dt) oacc[dt] = mfma16(pa0, vf[0][dt], oacc[dt]);
#pragma unroll
        for (int dt = 0; dt < 4; ++dt) oacc[dt] = mfma16(pa1, vf[1][dt], oacc[dt]);

        // One barrier per tile: reads of buf[cur] done + buf[cur^1] resident.
        __syncthreads();
    }

    // Row-sum reduce across the 16 l16-lanes of each quad
    for (int off = 1; off < 16; off <<= 1)
#pragma unroll
        for (int r = 0; r < 4; ++r)
            l_run[r] += __shfl_xor(l_run[r], off, 64);

    float inv[4];
#pragma unroll
    for (int r = 0; r < 4; ++r) inv[r] = 1.0f / l_run[r];

    // Direct per-wave store: lane holds O[qw+quad*4+r][dt*16+l16] (C layout).
    unsigned short* ob = &O[((size_t)(b * SS + qw + quad * 4)) * DD + h * 64 + l16];
#pragma unroll
    for (int r = 0; r < 4; ++r)
#pragma unroll
        for (int dt = 0; dt < 4; ++dt)
            ob[(size_t)r * DD + dt * 16] = f2bf(oacc[dt][r] * inv[r]);
}

// ---------------------------------------------------------------------------
extern "C" void kernel_launch(void* const* d_in, const int* in_sizes, int n_in,
                              void* d_out, int out_size, void* d_ws, size_t ws_size,
                              hipStream_t stream)
{
    const float* X  = (const float*)d_in[0];
    const float* Wq = (const float*)d_in[1];
    const float* Wk = (const float*)d_in[2];
    const float* Wv = (const float*)d_in[3];
    const float* Wo = (const float*)d_in[4];
    float* Out = (float*)d_out;

    // d_ws layout (fast path, needs 3*XSZ u16 = 18.9MB; guard at 25.2MB):
    //   [0,XSZ)      Qb   (Q bf16, later attn output in-place)
    //   [XSZ,2XSZ)   Kb   (K bf16; reused for bf16 Wo after attn)
    //   [2XSZ,3XSZ)  Xb   (X bf16, dead after gemm_qkv128)
    // d_out (2*XSZ u16): [0,XSZ) = V^T bf16 (dead before gemm_o writes);
    //   [XSZ,+3WSZ) = bf16 Wq,Wk,Wv (dead after the QKV GEMM).
    unsigned short* Qb  = (unsigned short*)d_ws;
    unsigned short* Kb  = Qb + XSZ;
    unsigned short* Xb  = Kb + XSZ;
    unsigned short* Vtb = (unsigned short*)d_out;
    unsigned short* Wqb = Vtb + XSZ;
    unsigned short* Wkb = Wqb + WSZ;
    unsigned short* Wvb = Wkb + WSZ;

    dim3 blk(256);
    dim3 g2(HH, BB, SS / 64);                       // attention grid
    dim3 g3(DD / 64, MM / 64);                      // out-projection grid

    if (ws_size >= (size_t)8 * XSZ) {               // fast path (25.2 MB guard)
        cvt_x3<<<4800, blk, 0, stream>>>(Wq, Wk, Wv, X, Wqb, Xb);

        dim3 g1(2304 / 128, MM / 128);              // 576 blocks: 128x128 QKV dbuf
        gemm_qkv128<<<g1, blk, 0, stream>>>(Xb, Wqb, Wkb, Wvb, Qb, Kb, Vtb);

        attn_ls<<<g2, blk, 0, stream>>>(Qb, Kb, Vtb, Qb);

        cvt_wo<<<576, blk, 0, stream>>>(Wo, Kb);    // Kb dead after attn

        gemm_o<<<g3, blk, 0, stream>>>(Qb, Kb, Out);
    } else {                                        // R16-verified fallback
        cvt_w3<<<1728, blk, 0, stream>>>(Wq, Wk, Wv, Wqb);

        dim3 g1(DD / 64, MM / 64);
        gemm_qkv64<<<g1, blk, 0, stream>>>(X, Wqb, Wkb, Wvb, Qb, Kb, Vtb);

        attn_ls<<<g2, blk, 0, stream>>>(Qb, Kb, Vtb, Qb);

        cvt_wo<<<576, blk, 0, stream>>>(Wo, Kb);

        gemm_o<<<g3, blk, 0, stream>>>(Qb, Kb, Out);
    }
}

// Round 7
// 166.470 us; speedup vs baseline: 1.0442x; 1.0119x over previous
//
#include <hip/hip_runtime.h>
#include <stdint.h>

// Problem constants (fixed by the reference)
#define BB   2
#define SS   2048
#define DD   768
#define HH   12
#define MM   (BB*SS)          // 4096 rows in all GEMMs
#define XSZ  (MM*DD)          // 3,145,728
#define WSZ  (DD*DD)          //   589,824

typedef __bf16 v8bf __attribute__((ext_vector_type(8)));   // 8 bf16 = 4 VGPRs (MFMA A/B frag)
typedef float  v4f  __attribute__((ext_vector_type(4)));   // MFMA C/D frag (16x16)

__device__ inline v4f mfma16(v8bf a, v8bf b, v4f c) {
    return __builtin_amdgcn_mfma_f32_16x16x32_bf16(a, b, c, 0, 0, 0);
}

// float -> bf16 bits, round-to-nearest-even
__device__ inline unsigned short f2bf(float f) {
    union { float f; uint32_t u; } v; v.f = f;
    return (unsigned short)((v.u + 0x7FFFu + ((v.u >> 16) & 1u)) >> 16);
}

// 8 contiguous fp32 -> 8 bf16 packed into 16 bytes (VGPR staging path)
__device__ inline uint4 cvt8(const float* __restrict__ p) {
    uint4 out;
    unsigned short* s = (unsigned short*)&out;
#pragma unroll
    for (int j = 0; j < 8; ++j) s[j] = f2bf(p[j]);
    return out;
}

// Async 16B global->LDS copy (gfx950). LDS dest is wave-uniform base + lane*16B.
__device__ __forceinline__ void gld_lds16(const unsigned short* g, unsigned short* l) {
    __builtin_amdgcn_global_load_lds(
        (const __attribute__((address_space(1))) void*)g,
        (__attribute__((address_space(3))) void*)l, 16, 0, 0);
}

// ---------------------------------------------------------------------------
// R21: fused QKV projection, 64x64 tile (R16-verified structure), ALL-fp32
// inputs with in-register cvt8 conversion during staging. Why: (a) R19/R20
// showed the 128^2 tile is grid-starved at this shape (576 blocks = 2.25/CU,
// MfmaUtil 11%, ~318 TF = exactly the m102 curve's ceiling for this scale) and
// the 64^2 fused ran faster (~39us); (b) totals reconstruction across R0-R20
// shows ~11us of inter-dispatch overhead per kernel transition -- folding the
// conversions into the GEMMs cuts the pipeline from 5 kernels to 3 (launch
// overhead was the 2nd-largest line item). VALUBusy was 7% -> the extra cvt8
// work rides under the existing latency stalls.
// A (X fp32) and all three W (fp32) are cvt8-staged with XOR-swizzled
// ds_write (byte ^= (row&7)<<4); frag reads XOR with (l16&7)<<4 -- verified
// involution (R16). 24 MFMA/wave per BK=64 step. Grid (12,64)=768 = 3/CU,
// XCD-chunked (768%8==0). Bit-identical output to the R16/R20 path (same
// f2bf rounding, same K-ascending accumulation order).
// ---------------------------------------------------------------------------
__global__ __launch_bounds__(256) void gemm_qkv64f(
    const float* __restrict__ X,
    const float* __restrict__ Wq,
    const float* __restrict__ Wk,
    const float* __restrict__ Wv,
    unsigned short* __restrict__ Qo,
    unsigned short* __restrict__ Ko,
    unsigned short* __restrict__ Vo)
{
    __shared__ __align__(16) unsigned short As[64 * 64];
    __shared__ __align__(16) unsigned short Bs[3][64 * 64];

    const int flat = (int)(blockIdx.y * gridDim.x + blockIdx.x);
    const int sw   = (flat & 7) * 96 + (flat >> 3);   // XCD-chunked, bijective
    const int m0   = (sw / 12) * 64;
    const int n0   = (sw % 12) * 64;

    const int tid  = threadIdx.x;
    const int wave = tid >> 6, lane = tid & 63;
    const int quad = lane >> 4, l16 = lane & 15;
    const int waveM = (wave >> 1) * 32, waveN = (wave & 1) * 32;

    // cvt8 staging geometry: thread covers row rA = tid>>2, 16 elems at cA.
    const int rA  = tid >> 2;
    const int cA  = (tid & 3) * 16;
    const int rxA = (rA & 7) << 4;              // row-XOR (bytes, 16B granule)
    const int swz = (l16 & 7) << 4;             // read-side XOR (bytes)

    v4f acc[3][2][2] = {};

    const float* ap = X  + (size_t)(m0 + rA) * DD + cA;
    const float* w0 = Wq + (size_t)(n0 + rA) * DD + cA;
    const float* w1 = Wk + (size_t)(n0 + rA) * DD + cA;
    const float* w2 = Wv + (size_t)(n0 + rA) * DD + cA;

    for (int kt = 0; kt < DD; kt += 64) {
        __syncthreads();                        // prev-iter frag reads done
        // A: 16 fp32 -> bf16, two swizzled ds_write_b128
        *(uint4*)((char*)As + rA * 128 + ((cA * 2)      ^ rxA)) = cvt8(ap + kt);
        *(uint4*)((char*)As + rA * 128 + ((cA * 2 + 16) ^ rxA)) = cvt8(ap + kt + 8);
        // B: 3 weights, same geometry (fp32 -> bf16, swizzled ds_write)
        *(uint4*)((char*)&Bs[0][0] + rA * 128 + ((cA * 2)      ^ rxA)) = cvt8(w0 + kt);
        *(uint4*)((char*)&Bs[0][0] + rA * 128 + ((cA * 2 + 16) ^ rxA)) = cvt8(w0 + kt + 8);
        *(uint4*)((char*)&Bs[1][0] + rA * 128 + ((cA * 2)      ^ rxA)) = cvt8(w1 + kt);
        *(uint4*)((char*)&Bs[1][0] + rA * 128 + ((cA * 2 + 16) ^ rxA)) = cvt8(w1 + kt + 8);
        *(uint4*)((char*)&Bs[2][0] + rA * 128 + ((cA * 2)      ^ rxA)) = cvt8(w2 + kt);
        *(uint4*)((char*)&Bs[2][0] + rA * 128 + ((cA * 2 + 16) ^ rxA)) = cvt8(w2 + kt + 8);
        __syncthreads();                        // staging visible (lgkm drain)

        v8bf af[2][2];
#pragma unroll
        for (int mi = 0; mi < 2; ++mi) {
            const char* arow = (const char*)As + (size_t)(waveM + mi * 16 + l16) * 128;
#pragma unroll
            for (int kf = 0; kf < 2; ++kf)
                af[mi][kf] = *(const v8bf*)(arow + ((kf * 64 + quad * 16) ^ swz));
        }
#pragma unroll
        for (int z = 0; z < 3; ++z) {
            v8bf bfr[2][2];
#pragma unroll
            for (int ni = 0; ni < 2; ++ni) {
                const char* brow = (const char*)&Bs[z][0] + (size_t)(waveN + ni * 16 + l16) * 128;
#pragma unroll
                for (int kf = 0; kf < 2; ++kf)
                    bfr[ni][kf] = *(const v8bf*)(brow + ((kf * 64 + quad * 16) ^ swz));
            }
#pragma unroll
            for (int mi = 0; mi < 2; ++mi)
#pragma unroll
                for (int ni = 0; ni < 2; ++ni) {
                    acc[z][mi][ni] = mfma16(af[mi][0], bfr[ni][0], acc[z][mi][ni]);
                    acc[z][mi][ni] = mfma16(af[mi][1], bfr[ni][1], acc[z][mi][ni]);
                }
        }
    }

    // Epilogue: C/D layout col=l16, row=quad*4+r (verified formula).
    // z=0 -> Q (B,S,D); z=1 -> K (B,S,D); z=2 -> V transposed (B,H,64,S).
#pragma unroll
    for (int mi = 0; mi < 2; ++mi)
#pragma unroll
        for (int ni = 0; ni < 2; ++ni)
#pragma unroll
            for (int r = 0; r < 4; ++r) {
                const int row = m0 + waveM + mi * 16 + quad * 4 + r;
                const int col = n0 + waveN + ni * 16 + l16;
                Qo[(size_t)row * DD + col] = f2bf(acc[0][mi][ni][r]);
                Ko[(size_t)row * DD + col] = f2bf(acc[1][mi][ni][r]);
                const int b = row >> 11, s = row & 2047;
                const int h = col >> 6,  dk = col & 63;
                Vo[(((size_t)(b * HH + h)) * 64 + dk) * SS + s] = f2bf(acc[2][mi][ni][r]);
            }
}

// ---------------------------------------------------------------------------
// R21 out-projection: 64x64, BK=64, double-buffered T3 2-phase (R20-verified
// loop, gained ~5us over the single-buffered version). A = attn output bf16
// via global_load_lds (source-preswizzled); W = Wo fp32 via cvt8 swizzled
// ds_write (fuses away the cvt_wo launch). One __syncthreads per K-step
// (drains vm for A and lgkm for B). Grid (12,64)=768 = 3/CU, XCD-chunked.
// ---------------------------------------------------------------------------
__global__ __launch_bounds__(256) void gemm_of(
    const unsigned short* __restrict__ A,
    const float* __restrict__ W,
    float* __restrict__ C)
{
    __shared__ __align__(16) unsigned short As[2][64 * 64];
    __shared__ __align__(16) unsigned short Bs[2][64 * 64];

    const int flat = (int)(blockIdx.y * gridDim.x + blockIdx.x);  // gx=12
    const int sw   = (flat & 7) * 96 + (flat >> 3);
    const int m0   = (sw / 12) * 64;
    const int n0   = (sw % 12) * 64;

    const int tid  = threadIdx.x;
    const int wave = tid >> 6, lane = tid & 63;
    const int quad = lane >> 4, l16 = lane & 15;
    const int waveM = (wave >> 1) * 32, waveN = (wave & 1) * 32;

    // A staging (async): rows wave*8+(lane>>3) (+32), source col pre-swizzled.
    const int rB  = wave * 8 + (lane >> 3);
    const int cB  = ((lane & 7) ^ (lane >> 3)) * 8;
    // W staging (cvt8): row rW = tid>>2, 16 elems at cW, swizzled ds_write.
    const int rW  = tid >> 2;
    const int cW  = (tid & 3) * 16;
    const int rxW = (rW & 7) << 4;
    const int swz = (l16 & 7) << 4;

    const unsigned short* a0 = A + (size_t)(m0 + rB) * DD + cB;
    const float*          b0 = W + (size_t)(n0 + rW) * DD + cW;

    v4f acc[2][2] = {};

    // Prologue: stage tile 0 into buffer 0
    gld_lds16(a0,           &As[0][wave * 512]);
    gld_lds16(a0 + 32 * DD, &As[0][2048 + wave * 512]);
    *(uint4*)((char*)&Bs[0][0] + rW * 128 + ((cW * 2)      ^ rxW)) = cvt8(b0);
    *(uint4*)((char*)&Bs[0][0] + rW * 128 + ((cW * 2 + 16) ^ rxW)) = cvt8(b0 + 8);
    __syncthreads();

    int cur = 0;
    for (int kt = 0; kt < DD; kt += 64) {
        if (kt + 64 < DD) {                     // stage NEXT tile
            gld_lds16(a0 + kt + 64,           &As[cur ^ 1][wave * 512]);
            gld_lds16(a0 + kt + 64 + 32 * DD, &As[cur ^ 1][2048 + wave * 512]);
            *(uint4*)((char*)&Bs[cur ^ 1][0] + rW * 128 + ((cW * 2)      ^ rxW)) = cvt8(b0 + kt + 64);
            *(uint4*)((char*)&Bs[cur ^ 1][0] + rW * 128 + ((cW * 2 + 16) ^ rxW)) = cvt8(b0 + kt + 64 + 8);
        }
#pragma unroll
        for (int kf = 0; kf < 2; ++kf) {
            v8bf af[2], bfr[2];
#pragma unroll
            for (int i = 0; i < 2; ++i) {
                af[i]  = *(const v8bf*)((const char*)&As[cur][0] +
                          (size_t)(waveM + i * 16 + l16) * 128 + ((kf * 64 + quad * 16) ^ swz));
                bfr[i] = *(const v8bf*)((const char*)&Bs[cur][0] +
                          (size_t)(waveN + i * 16 + l16) * 128 + ((kf * 64 + quad * 16) ^ swz));
            }
#pragma unroll
            for (int mi = 0; mi < 2; ++mi)
#pragma unroll
                for (int ni = 0; ni < 2; ++ni)
                    acc[mi][ni] = mfma16(af[mi], bfr[ni], acc[mi][ni]);
        }
        __syncthreads();   // frag reads of buf[cur] done + buf[cur^1] resident
        cur ^= 1;
    }

#pragma unroll
    for (int mi = 0; mi < 2; ++mi)
#pragma unroll
        for (int ni = 0; ni < 2; ++ni)
#pragma unroll
            for (int r = 0; r < 4; ++r) {
                const int row = m0 + waveM + mi * 16 + quad * 4 + r;
                const int col = n0 + waveN + ni * 16 + l16;
                C[(size_t)row * DD + col] = acc[mi][ni][r];
            }
}

// ---------------------------------------------------------------------------
// R15 attention (verified): LDS-staged, wave-private q-strips, double-buffered
// K/V via global_load_lds with XOR-swizzle (source-preswizzled), one barrier
// per tile, no merge phase. Unchanged.
// ---------------------------------------------------------------------------
__global__ __launch_bounds__(256, 3) void attn_ls(
    const unsigned short* Q,                 // (B,S,D) bf16 (aliases O)
    const unsigned short* __restrict__ Kg,   // (B,S,D) bf16
    const unsigned short* __restrict__ Vt,   // (B,H,64,S) bf16 transposed
    unsigned short* O)                       // (B,S,D) bf16
{
    const int h = blockIdx.x, b = blockIdx.y;
    const int qs = (SS / 64 - 1 - (int)blockIdx.z) * 64;   // LPT: heavy first
    const int tid  = threadIdx.x;
    const int wave = tid >> 6, lane = tid & 63;
    const int quad = lane >> 4, l16 = lane & 15;
    const int qw = qs + wave * 16;           // this wave's private q rows
    const float scale = 0.125f;              // 1/sqrt(64)

    __shared__ __align__(16) unsigned short Ks[2][4096];   // 2 x 64x64 bf16, swizzled
    __shared__ __align__(16) unsigned short Vs[2][4096];   // 2 x 64x64 bf16, swizzled
    __shared__ __align__(16) unsigned short Ps[4][16 * 72];// per-wave P buffer

    // Q frags for this wave's 16 rows (read before any O write: in-place safe)
    v8bf qf0, qf1;
    {
        const unsigned short* qp = &Q[((size_t)(b * SS + qw + l16)) * DD + h * 64];
        qf0 = *(const v8bf*)(qp + quad * 8);
        qf1 = *(const v8bf*)(qp + 32 + quad * 8);
    }

    const int NT = qs / 64 + 1;              // causal k-tiles, SAME for all 4 waves
    const char* kgb = (const char*)&Kg[(size_t)(b * SS) * DD + h * 64];
    const char* vgb = (const char*)&Vt[((size_t)(b * HH + h) * 64) * SS];

    const int rA = wave * 8 + (lane >> 3);               // rows rA and rA+32
    const int oA = ((lane & 7) * 16) ^ ((rA & 7) << 4);  // swizzled in-row byte
    const int swz = (l16 & 7) << 4;                      // read-side XOR

    v4f oacc[4] = {};
    float l_run[4] = {0.f, 0.f, 0.f, 0.f};
    unsigned short* pw = &Ps[wave][0];

    // Prologue: stage tile 0 into buffer 0
    gld_lds16((const unsigned short*)(kgb + (size_t)rA        * (DD * 2) + oA), &Ks[0][wave * 512]);
    gld_lds16((const unsigned short*)(kgb + (size_t)(rA + 32) * (DD * 2) + oA), &Ks[0][2048 + wave * 512]);
    gld_lds16((const unsigned short*)(vgb + (size_t)rA        * (SS * 2) + oA), &Vs[0][wave * 512]);
    gld_lds16((const unsigned short*)(vgb + (size_t)(rA + 32) * (SS * 2) + oA), &Vs[0][2048 + wave * 512]);
    __syncthreads();   // drains vmcnt: tile 0 resident

    for (int kt = 0; kt < NT; ++kt) {
        const int cur = kt & 1;
        const int kb  = kt * 64;

        // Async-stage NEXT tile into the other buffer
        if (kt + 1 < NT) {
            const size_t kb2 = (size_t)(kb + 64);
            gld_lds16((const unsigned short*)(kgb + (kb2 + rA)      * (DD * 2) + oA), &Ks[cur ^ 1][wave * 512]);
            gld_lds16((const unsigned short*)(kgb + (kb2 + rA + 32) * (DD * 2) + oA), &Ks[cur ^ 1][2048 + wave * 512]);
            gld_lds16((const unsigned short*)(vgb + (size_t)rA        * (SS * 2) + kb2 * 2 + oA), &Vs[cur ^ 1][wave * 512]);
            gld_lds16((const unsigned short*)(vgb + (size_t)(rA + 32) * (SS * 2) + kb2 * 2 + oA), &Vs[cur ^ 1][2048 + wave * 512]);
        }

        const char* ksb = (const char*)&Ks[cur][0];
        const char* vsb = (const char*)&Vs[cur][0];

        // K frags from swizzled LDS: row = nk*16+l16, cols half*32 + quad*8..
        v8bf kf0[4], kf1[4];
#pragma unroll
        for (int nk = 0; nk < 4; ++nk) {
            const char* krow = ksb + (size_t)(nk * 16 + l16) * 128;
            kf0[nk] = *(const v8bf*)(krow + ((quad * 16) ^ swz));
            kf1[nk] = *(const v8bf*)(krow + ((64 + quad * 16) ^ swz));
        }

        // S = Q K^T (16 q-rows x 64 keys), f32 accumulate
        v4f sacc[4] = {};
#pragma unroll
        for (int nk = 0; nk < 4; ++nk) {
            sacc[nk] = mfma16(qf0, kf0[nk], sacc[nk]);
            sacc[nk] = mfma16(qf1, kf1[nk], sacc[nk]);
        }

        // fixed-base softmax: p = exp(s/8); mask only on the diagonal tile
        const bool diag = (kt == NT - 1);
        float pv[4][4];
#pragma unroll
        for (int nk = 0; nk < 4; ++nk)
#pragma unroll
            for (int r = 0; r < 4; ++r) {
                float p = __expf(sacc[nk][r] * scale);
                if (diag) {
                    int key  = kb + nk * 16 + l16;
                    int qrow = qw + quad * 4 + r;
                    if (key > qrow) p = 0.0f;
                }
                pv[nk][r] = p;
                l_run[r] += p;
            }

        // V frags (issued before the P round-trip so latency overlaps it)
        v8bf vf[2][4];
#pragma unroll
        for (int kc = 0; kc < 2; ++kc)
#pragma unroll
            for (int dt = 0; dt < 4; ++dt) {
                const char* vr = vsb + (size_t)(dt * 16 + l16) * 128;
                vf[kc][dt] = *(const v8bf*)(vr + ((kc * 64 + quad * 16) ^ swz));
            }

        // P: C-layout -> per-wave LDS (stride 72) -> A-layout frags
#pragma unroll
        for (int nk = 0; nk < 4; ++nk)
#pragma unroll
            for (int r = 0; r < 4; ++r)
                pw[(quad * 4 + r) * 72 + nk * 16 + l16] = f2bf(pv[nk][r]);
        __asm__ volatile("" ::: "memory");

        v8bf pa0 = *(const v8bf*)(&pw[l16 * 72 + quad * 8]);
        v8bf pa1 = *(const v8bf*)(&pw[l16 * 72 + 32 + quad * 8]);
#pragma unroll
        for (int dt = 0; dt < 4; ++dt) oacc[dt] = mfma16(pa0, vf[0][dt], oacc[dt]);
#pragma unroll
        for (int dt = 0; dt < 4; ++dt) oacc[dt] = mfma16(pa1, vf[1][dt], oacc[dt]);

        // One barrier per tile: reads of buf[cur] done + buf[cur^1] resident.
        __syncthreads();
    }

    // Row-sum reduce across the 16 l16-lanes of each quad
    for (int off = 1; off < 16; off <<= 1)
#pragma unroll
        for (int r = 0; r < 4; ++r)
            l_run[r] += __shfl_xor(l_run[r], off, 64);

    float inv[4];
#pragma unroll
    for (int r = 0; r < 4; ++r) inv[r] = 1.0f / l_run[r];

    // Direct per-wave store: lane holds O[qw+quad*4+r][dt*16+l16] (C layout).
    unsigned short* ob = &O[((size_t)(b * SS + qw + quad * 4)) * DD + h * 64 + l16];
#pragma unroll
    for (int r = 0; r < 4; ++r)
#pragma unroll
        for (int dt = 0; dt < 4; ++dt)
            ob[(size_t)r * DD + dt * 16] = f2bf(oacc[dt][r] * inv[r]);
}

// ---------------------------------------------------------------------------
extern "C" void kernel_launch(void* const* d_in, const int* in_sizes, int n_in,
                              void* d_out, int out_size, void* d_ws, size_t ws_size,
                              hipStream_t stream)
{
    const float* X  = (const float*)d_in[0];
    const float* Wq = (const float*)d_in[1];
    const float* Wk = (const float*)d_in[2];
    const float* Wv = (const float*)d_in[3];
    const float* Wo = (const float*)d_in[4];
    float* Out = (float*)d_out;

    // d_ws (needs 2*XSZ u16 = 12.6MB, verified available since R15):
    //   [0,XSZ)    Qb (Q bf16, attn output in-place)
    //   [XSZ,2XSZ) Kb (K bf16)
    // d_out: [0,XSZ) u16 = V^T bf16 (dead before gemm_of writes fp32 output).
    unsigned short* Qb  = (unsigned short*)d_ws;
    unsigned short* Kb  = Qb + XSZ;
    unsigned short* Vtb = (unsigned short*)d_out;

    dim3 blk(256);

    dim3 g1(DD / 64, MM / 64);                      // 768 blocks: fused QKV (all-fp32 in)
    gemm_qkv64f<<<g1, blk, 0, stream>>>(X, Wq, Wk, Wv, Qb, Kb, Vtb);

    dim3 g2(HH, BB, SS / 64);                       // 768 blocks: LDS-staged attn
    attn_ls<<<g2, blk, 0, stream>>>(Qb, Kb, Vtb, Qb);

    dim3 g3(DD / 64, MM / 64);                      // 768 blocks: out projection
    gemm_of<<<g3, blk, 0, stream>>>(Qb, Wo, Out);
}

// Round 9
// 153.771 us; speedup vs baseline: 1.1304x; 1.0826x over previous
//
#include <hip/hip_runtime.h>
#include <stdint.h>

// Problem constants (fixed by the reference)
#define BB   2
#define SS   2048
#define DD   768
#define HH   12
#define MM   (BB*SS)          // 4096 rows in all GEMMs
#define XSZ  (MM*DD)          // 3,145,728
#define WSZ  (DD*DD)          //   589,824

typedef __bf16 v8bf __attribute__((ext_vector_type(8)));   // 8 bf16 = 4 VGPRs (MFMA A/B frag)
typedef float  v4f  __attribute__((ext_vector_type(4)));   // MFMA C/D frag (16x16)

__device__ inline v4f mfma16(v8bf a, v8bf b, v4f c) {
    return __builtin_amdgcn_mfma_f32_16x16x32_bf16(a, b, c, 0, 0, 0);
}

// float -> bf16 bits, round-to-nearest-even
__device__ inline unsigned short f2bf(float f) {
    union { float f; uint32_t u; } v; v.f = f;
    return (unsigned short)((v.u + 0x7FFFu + ((v.u >> 16) & 1u)) >> 16);
}

// 8 contiguous fp32 -> 8 bf16 packed into 16 bytes (VGPR staging path)
__device__ inline uint4 cvt8(const float* __restrict__ p) {
    uint4 out;
    unsigned short* s = (unsigned short*)&out;
#pragma unroll
    for (int j = 0; j < 8; ++j) s[j] = f2bf(p[j]);
    return out;
}

// Async 16B global->LDS copy (gfx950). LDS dest is wave-uniform base + lane*16B.
__device__ __forceinline__ void gld_lds16(const unsigned short* g, unsigned short* l) {
    __builtin_amdgcn_global_load_lds(
        (const __attribute__((address_space(1))) void*)g,
        (__attribute__((address_space(3))) void*)l, 16, 0, 0);
}

// ---------------------------------------------------------------------------
// R16-verified: fp32 -> bf16 for Wq,Wk,Wv into d_out's second half (3*WSZ
// elems = 1728 blocks x 256 thr x 4 elems exactly). Region dead until gemm_of
// writes the fp32 output. ~10.6MB traffic => ~2.5us.
// (R23 = byte-identical resubmit of R22: that bench died as "container failed
// twice" with zero profile output; every kernel here has individually passed
// on-harness in R15/R16/R21, so the failure is attributed to infra per the
// R17/R18->R19 precedent. One identical retry, no confounding edits.)
// ---------------------------------------------------------------------------
__global__ __launch_bounds__(256) void cvt_w3(
    const float* __restrict__ Wq, const float* __restrict__ Wk,
    const float* __restrict__ Wv, unsigned short* __restrict__ dst)
{
    long i4 = ((long)blockIdx.x * 256 + threadIdx.x) * 4;
    int t = (int)(i4 / WSZ);
    long off = i4 - (long)t * WSZ;
    const float* s = (t == 0) ? Wq : (t == 1) ? Wk : Wv;
    float4 v = *(const float4*)(s + off);
    ushort4 o;
    o.x = f2bf(v.x); o.y = f2bf(v.y); o.z = f2bf(v.z); o.w = f2bf(v.w);
    *(ushort4*)(dst + (size_t)t * WSZ + off) = o;
}

// ---------------------------------------------------------------------------
// R16-verified fused 64x64 QKV: one block stages the 64x64 X-tile ONCE
// (cvt8 fp32->bf16, XOR-swizzled ds_write) and runs it against 3 bf16 weight
// tiles staged async via global_load_lds (source col pre-swizzled; LDS linear
// dest -- both-sides involution). 24 MFMA/wave per BK=64 step. Grid (12,64)
// = 768 blocks = 3/CU, XCD-chunked (768%8==0; all 12 n-tiles of an m-strip on
// one XCD -> X strip L2-resident). Measured ~37us inferred in R16 vs 46-57
// for the 128^2 / all-fp32 variants (R19-R21 experiments, both concluded).
// ---------------------------------------------------------------------------
__global__ __launch_bounds__(256) void gemm_qkv64(
    const float* __restrict__ X,
    const unsigned short* __restrict__ Wq,
    const unsigned short* __restrict__ Wk,
    const unsigned short* __restrict__ Wv,
    unsigned short* __restrict__ Qo,
    unsigned short* __restrict__ Ko,
    unsigned short* __restrict__ Vo)
{
    __shared__ __align__(16) unsigned short As[64 * 64];
    __shared__ __align__(16) unsigned short Bs[3][64 * 64];

    const int flat = (int)(blockIdx.y * gridDim.x + blockIdx.x);
    const int sw   = (flat & 7) * 96 + (flat >> 3);
    const int m0   = (sw / 12) * 64;
    const int n0   = (sw % 12) * 64;

    const int tid  = threadIdx.x;
    const int wave = tid >> 6, lane = tid & 63;
    const int quad = lane >> 4, l16 = lane & 15;
    const int waveM = (wave >> 1) * 32, waveN = (wave & 1) * 32;

    const int rA  = tid >> 2;
    const int cA  = (tid & 3) * 16;
    const int rxA = (rA & 7) << 4;

    const int rB  = wave * 8 + (lane >> 3);
    const int cB  = ((lane & 7) ^ (lane >> 3)) * 8;
    const int swz = (l16 & 7) << 4;

    v4f acc[3][2][2] = {};

    const float* ap0 = X + (size_t)(m0 + rA) * DD + cA;
    const unsigned short* w0 = Wq + (size_t)(n0 + rB) * DD + cB;
    const unsigned short* w1 = Wk + (size_t)(n0 + rB) * DD + cB;
    const unsigned short* w2 = Wv + (size_t)(n0 + rB) * DD + cB;

    for (int kt = 0; kt < DD; kt += 64) {
        __syncthreads();
        *(uint4*)((char*)As + rA * 128 + ((cA * 2)      ^ rxA)) = cvt8(ap0 + kt);
        *(uint4*)((char*)As + rA * 128 + ((cA * 2 + 16) ^ rxA)) = cvt8(ap0 + kt + 8);
        gld_lds16(w0 + kt,           &Bs[0][wave * 512]);
        gld_lds16(w0 + kt + 32 * DD, &Bs[0][2048 + wave * 512]);
        gld_lds16(w1 + kt,           &Bs[1][wave * 512]);
        gld_lds16(w1 + kt + 32 * DD, &Bs[1][2048 + wave * 512]);
        gld_lds16(w2 + kt,           &Bs[2][wave * 512]);
        gld_lds16(w2 + kt + 32 * DD, &Bs[2][2048 + wave * 512]);
        __syncthreads();

        v8bf af[2][2];
#pragma unroll
        for (int mi = 0; mi < 2; ++mi) {
            const char* arow = (const char*)As + (size_t)(waveM + mi * 16 + l16) * 128;
#pragma unroll
            for (int kf = 0; kf < 2; ++kf)
                af[mi][kf] = *(const v8bf*)(arow + ((kf * 64 + quad * 16) ^ swz));
        }
#pragma unroll
        for (int z = 0; z < 3; ++z) {
            v8bf bfr[2][2];
#pragma unroll
            for (int ni = 0; ni < 2; ++ni) {
                const char* brow = (const char*)&Bs[z][0] + (size_t)(waveN + ni * 16 + l16) * 128;
#pragma unroll
                for (int kf = 0; kf < 2; ++kf)
                    bfr[ni][kf] = *(const v8bf*)(brow + ((kf * 64 + quad * 16) ^ swz));
            }
#pragma unroll
            for (int mi = 0; mi < 2; ++mi)
#pragma unroll
                for (int ni = 0; ni < 2; ++ni) {
                    acc[z][mi][ni] = mfma16(af[mi][0], bfr[ni][0], acc[z][mi][ni]);
                    acc[z][mi][ni] = mfma16(af[mi][1], bfr[ni][1], acc[z][mi][ni]);
                }
        }
    }

    // Epilogue: C/D layout col=l16, row=quad*4+r (verified formula).
    // z=0 -> Q (B,S,D); z=1 -> K (B,S,D); z=2 -> V transposed (B,H,64,S).
#pragma unroll
    for (int mi = 0; mi < 2; ++mi)
#pragma unroll
        for (int ni = 0; ni < 2; ++ni)
#pragma unroll
            for (int r = 0; r < 4; ++r) {
                const int row = m0 + waveM + mi * 16 + quad * 4 + r;
                const int col = n0 + waveN + ni * 16 + l16;
                Qo[(size_t)row * DD + col] = f2bf(acc[0][mi][ni][r]);
                Ko[(size_t)row * DD + col] = f2bf(acc[1][mi][ni][r]);
                const int b = row >> 11, s = row & 2047;
                const int h = col >> 6,  dk = col & 63;
                Vo[(((size_t)(b * HH + h)) * 64 + dk) * SS + s] = f2bf(acc[2][mi][ni][r]);
            }
}

// ---------------------------------------------------------------------------
// R21-verified out-projection: 64x64, BK=64, double-buffered T3 2-phase.
// A = attn output bf16 via global_load_lds (source-preswizzled); W = Wo fp32
// via cvt8 swizzled ds_write (only ONE weight tile per step -> the cvt8 VALU
// cost that sank the fused QKV is 1/3 here and rides under the A-side async).
// Grid (12,64)=768 = 3/CU, XCD-chunked. LDS 32KB.
// ---------------------------------------------------------------------------
__global__ __launch_bounds__(256) void gemm_of(
    const unsigned short* __restrict__ A,
    const float* __restrict__ W,
    float* __restrict__ C)
{
    __shared__ __align__(16) unsigned short As[2][64 * 64];
    __shared__ __align__(16) unsigned short Bs[2][64 * 64];

    const int flat = (int)(blockIdx.y * gridDim.x + blockIdx.x);  // gx=12
    const int sw   = (flat & 7) * 96 + (flat >> 3);
    const int m0   = (sw / 12) * 64;
    const int n0   = (sw % 12) * 64;

    const int tid  = threadIdx.x;
    const int wave = tid >> 6, lane = tid & 63;
    const int quad = lane >> 4, l16 = lane & 15;
    const int waveM = (wave >> 1) * 32, waveN = (wave & 1) * 32;

    const int rB  = wave * 8 + (lane >> 3);
    const int cB  = ((lane & 7) ^ (lane >> 3)) * 8;
    const int rW  = tid >> 2;
    const int cW  = (tid & 3) * 16;
    const int rxW = (rW & 7) << 4;
    const int swz = (l16 & 7) << 4;

    const unsigned short* a0 = A + (size_t)(m0 + rB) * DD + cB;
    const float*          b0 = W + (size_t)(n0 + rW) * DD + cW;

    v4f acc[2][2] = {};

    // Prologue: stage tile 0 into buffer 0
    gld_lds16(a0,           &As[0][wave * 512]);
    gld_lds16(a0 + 32 * DD, &As[0][2048 + wave * 512]);
    *(uint4*)((char*)&Bs[0][0] + rW * 128 + ((cW * 2)      ^ rxW)) = cvt8(b0);
    *(uint4*)((char*)&Bs[0][0] + rW * 128 + ((cW * 2 + 16) ^ rxW)) = cvt8(b0 + 8);
    __syncthreads();

    int cur = 0;
    for (int kt = 0; kt < DD; kt += 64) {
        if (kt + 64 < DD) {                     // stage NEXT tile
            gld_lds16(a0 + kt + 64,           &As[cur ^ 1][wave * 512]);
            gld_lds16(a0 + kt + 64 + 32 * DD, &As[cur ^ 1][2048 + wave * 512]);
            *(uint4*)((char*)&Bs[cur ^ 1][0] + rW * 128 + ((cW * 2)      ^ rxW)) = cvt8(b0 + kt + 64);
            *(uint4*)((char*)&Bs[cur ^ 1][0] + rW * 128 + ((cW * 2 + 16) ^ rxW)) = cvt8(b0 + kt + 64 + 8);
        }
#pragma unroll
        for (int kf = 0; kf < 2; ++kf) {
            v8bf af[2], bfr[2];
#pragma unroll
            for (int i = 0; i < 2; ++i) {
                af[i]  = *(const v8bf*)((const char*)&As[cur][0] +
                          (size_t)(waveM + i * 16 + l16) * 128 + ((kf * 64 + quad * 16) ^ swz));
                bfr[i] = *(const v8bf*)((const char*)&Bs[cur][0] +
                          (size_t)(waveN + i * 16 + l16) * 128 + ((kf * 64 + quad * 16) ^ swz));
            }
#pragma unroll
            for (int mi = 0; mi < 2; ++mi)
#pragma unroll
                for (int ni = 0; ni < 2; ++ni)
                    acc[mi][ni] = mfma16(af[mi], bfr[ni], acc[mi][ni]);
        }
        __syncthreads();   // frag reads of buf[cur] done + buf[cur^1] resident
        cur ^= 1;
    }

#pragma unroll
    for (int mi = 0; mi < 2; ++mi)
#pragma unroll
        for (int ni = 0; ni < 2; ++ni)
#pragma unroll
            for (int r = 0; r < 4; ++r) {
                const int row = m0 + waveM + mi * 16 + quad * 4 + r;
                const int col = n0 + waveN + ni * 16 + l16;
                C[(size_t)row * DD + col] = acc[mi][ni][r];
            }
}

// ---------------------------------------------------------------------------
// R15 attention (verified): LDS-staged, wave-private q-strips, double-buffered
// K/V via global_load_lds with XOR-swizzle (source-preswizzled), one barrier
// per tile, no merge phase. Unchanged.
// ---------------------------------------------------------------------------
__global__ __launch_bounds__(256, 3) void attn_ls(
    const unsigned short* Q,                 // (B,S,D) bf16 (aliases O)
    const unsigned short* __restrict__ Kg,   // (B,S,D) bf16
    const unsigned short* __restrict__ Vt,   // (B,H,64,S) bf16 transposed
    unsigned short* O)                       // (B,S,D) bf16
{
    const int h = blockIdx.x, b = blockIdx.y;
    const int qs = (SS / 64 - 1 - (int)blockIdx.z) * 64;   // LPT: heavy first
    const int tid  = threadIdx.x;
    const int wave = tid >> 6, lane = tid & 63;
    const int quad = lane >> 4, l16 = lane & 15;
    const int qw = qs + wave * 16;           // this wave's private q rows
    const float scale = 0.125f;              // 1/sqrt(64)

    __shared__ __align__(16) unsigned short Ks[2][4096];   // 2 x 64x64 bf16, swizzled
    __shared__ __align__(16) unsigned short Vs[2][4096];   // 2 x 64x64 bf16, swizzled
    __shared__ __align__(16) unsigned short Ps[4][16 * 72];// per-wave P buffer

    // Q frags for this wave's 16 rows (read before any O write: in-place safe)
    v8bf qf0, qf1;
    {
        const unsigned short* qp = &Q[((size_t)(b * SS + qw + l16)) * DD + h * 64];
        qf0 = *(const v8bf*)(qp + quad * 8);
        qf1 = *(const v8bf*)(qp + 32 + quad * 8);
    }

    const int NT = qs / 64 + 1;              // causal k-tiles, SAME for all 4 waves
    const char* kgb = (const char*)&Kg[(size_t)(b * SS) * DD + h * 64];
    const char* vgb = (const char*)&Vt[((size_t)(b * HH + h) * 64) * SS];

    const int rA = wave * 8 + (lane >> 3);               // rows rA and rA+32
    const int oA = ((lane & 7) * 16) ^ ((rA & 7) << 4);  // swizzled in-row byte
    const int swz = (l16 & 7) << 4;                      // read-side XOR

    v4f oacc[4] = {};
    float l_run[4] = {0.f, 0.f, 0.f, 0.f};
    unsigned short* pw = &Ps[wave][0];

    // Prologue: stage tile 0 into buffer 0
    gld_lds16((const unsigned short*)(kgb + (size_t)rA        * (DD * 2) + oA), &Ks[0][wave * 512]);
    gld_lds16((const unsigned short*)(kgb + (size_t)(rA + 32) * (DD * 2) + oA), &Ks[0][2048 + wave * 512]);
    gld_lds16((const unsigned short*)(vgb + (size_t)rA        * (SS * 2) + oA), &Vs[0][wave * 512]);
    gld_lds16((const unsigned short*)(vgb + (size_t)(rA + 32) * (SS * 2) + oA), &Vs[0][2048 + wave * 512]);
    __syncthreads();   // drains vmcnt: tile 0 resident

    for (int kt = 0; kt < NT; ++kt) {
        const int cur = kt & 1;
        const int kb  = kt * 64;

        // Async-stage NEXT tile into the other buffer
        if (kt + 1 < NT) {
            const size_t kb2 = (size_t)(kb + 64);
            gld_lds16((const unsigned short*)(kgb + (kb2 + rA)      * (DD * 2) + oA), &Ks[cur ^ 1][wave * 512]);
            gld_lds16((const unsigned short*)(kgb + (kb2 + rA + 32) * (DD * 2) + oA), &Ks[cur ^ 1][2048 + wave * 512]);
            gld_lds16((const unsigned short*)(vgb + (size_t)rA        * (SS * 2) + kb2 * 2 + oA), &Vs[cur ^ 1][wave * 512]);
            gld_lds16((const unsigned short*)(vgb + (size_t)(rA + 32) * (SS * 2) + kb2 * 2 + oA), &Vs[cur ^ 1][2048 + wave * 512]);
        }

        const char* ksb = (const char*)&Ks[cur][0];
        const char* vsb = (const char*)&Vs[cur][0];

        // K frags from swizzled LDS: row = nk*16+l16, cols half*32 + quad*8..
        v8bf kf0[4], kf1[4];
#pragma unroll
        for (int nk = 0; nk < 4; ++nk) {
            const char* krow = ksb + (size_t)(nk * 16 + l16) * 128;
            kf0[nk] = *(const v8bf*)(krow + ((quad * 16) ^ swz));
            kf1[nk] = *(const v8bf*)(krow + ((64 + quad * 16) ^ swz));
        }

        // S = Q K^T (16 q-rows x 64 keys), f32 accumulate
        v4f sacc[4] = {};
#pragma unroll
        for (int nk = 0; nk < 4; ++nk) {
            sacc[nk] = mfma16(qf0, kf0[nk], sacc[nk]);
            sacc[nk] = mfma16(qf1, kf1[nk], sacc[nk]);
        }

        // fixed-base softmax: p = exp(s/8); mask only on the diagonal tile
        const bool diag = (kt == NT - 1);
        float pv[4][4];
#pragma unroll
        for (int nk = 0; nk < 4; ++nk)
#pragma unroll
            for (int r = 0; r < 4; ++r) {
                float p = __expf(sacc[nk][r] * scale);
                if (diag) {
                    int key  = kb + nk * 16 + l16;
                    int qrow = qw + quad * 4 + r;
                    if (key > qrow) p = 0.0f;
                }
                pv[nk][r] = p;
                l_run[r] += p;
            }

        // V frags (issued before the P round-trip so latency overlaps it)
        v8bf vf[2][4];
#pragma unroll
        for (int kc = 0; kc < 2; ++kc)
#pragma unroll
            for (int dt = 0; dt < 4; ++dt) {
                const char* vr = vsb + (size_t)(dt * 16 + l16) * 128;
                vf[kc][dt] = *(const v8bf*)(vr + ((kc * 64 + quad * 16) ^ swz));
            }

        // P: C-layout -> per-wave LDS (stride 72) -> A-layout frags
#pragma unroll
        for (int nk = 0; nk < 4; ++nk)
#pragma unroll
            for (int r = 0; r < 4; ++r)
                pw[(quad * 4 + r) * 72 + nk * 16 + l16] = f2bf(pv[nk][r]);
        __asm__ volatile("" ::: "memory");

        v8bf pa0 = *(const v8bf*)(&pw[l16 * 72 + quad * 8]);
        v8bf pa1 = *(const v8bf*)(&pw[l16 * 72 + 32 + quad * 8]);
#pragma unroll
        for (int dt = 0; dt < 4; ++dt) oacc[dt] = mfma16(pa0, vf[0][dt], oacc[dt]);
#pragma unroll
        for (int dt = 0; dt < 4; ++dt) oacc[dt] = mfma16(pa1, vf[1][dt], oacc[dt]);

        // One barrier per tile: reads of buf[cur] done + buf[cur^1] resident.
        __syncthreads();
    }

    // Row-sum reduce across the 16 l16-lanes of each quad
    for (int off = 1; off < 16; off <<= 1)
#pragma unroll
        for (int r = 0; r < 4; ++r)
            l_run[r] += __shfl_xor(l_run[r], off, 64);

    float inv[4];
#pragma unroll
    for (int r = 0; r < 4; ++r) inv[r] = 1.0f / l_run[r];

    // Direct per-wave store: lane holds O[qw+quad*4+r][dt*16+l16] (C layout).
    unsigned short* ob = &O[((size_t)(b * SS + qw + quad * 4)) * DD + h * 64 + l16];
#pragma unroll
    for (int r = 0; r < 4; ++r)
#pragma unroll
        for (int dt = 0; dt < 4; ++dt)
            ob[(size_t)r * DD + dt * 16] = f2bf(oacc[dt][r] * inv[r]);
}

// ---------------------------------------------------------------------------
extern "C" void kernel_launch(void* const* d_in, const int* in_sizes, int n_in,
                              void* d_out, int out_size, void* d_ws, size_t ws_size,
                              hipStream_t stream)
{
    const float* X  = (const float*)d_in[0];
    const float* Wq = (const float*)d_in[1];
    const float* Wk = (const float*)d_in[2];
    const float* Wv = (const float*)d_in[3];
    const float* Wo = (const float*)d_in[4];
    float* Out = (float*)d_out;

    // d_ws (needs 2*XSZ u16 = 12.6MB, verified since R15):
    //   [0,XSZ)    Qb (Q bf16, attn output in-place)
    //   [XSZ,2XSZ) Kb (K bf16)
    // d_out (2*XSZ u16): [0,XSZ) = V^T bf16 (dead before gemm_of's fp32
    //   output overwrites); [XSZ,+3WSZ) = bf16 Wq,Wk,Wv (dead after QKV GEMM).
    unsigned short* Qb  = (unsigned short*)d_ws;
    unsigned short* Kb  = Qb + XSZ;
    unsigned short* Vtb = (unsigned short*)d_out;
    unsigned short* Wqb = Vtb + XSZ;

    dim3 blk(256);

    cvt_w3<<<1728, blk, 0, stream>>>(Wq, Wk, Wv, Wqb);

    dim3 g1(DD / 64, MM / 64);                      // 768 blocks: fused QKV
    gemm_qkv64<<<g1, blk, 0, stream>>>(X, Wqb, Wqb + WSZ, Wqb + 2 * WSZ,
                                       Qb, Kb, Vtb);

    dim3 g2(HH, BB, SS / 64);                       // 768 blocks: LDS-staged attn
    attn_ls<<<g2, blk, 0, stream>>>(Qb, Kb, Vtb, Qb);

    dim3 g3(DD / 64, MM / 64);                      // 768 blocks: out projection
    gemm_of<<<g3, blk, 0, stream>>>(Qb, Wo, Out);
}